// Round 16
// baseline (266.013 us; speedup 1.0000x reference)
//
#include <hip/hip_runtime.h>

// ---------------------------------------------------------------------------
// GALE_FA: FLARE low-rank self-attn + context cross-attn + gated mix.
// R4: logits computed directly from x (k/q never materialized).
// R8: K-cut 1536->1024 (drop xl*Bhi), xs hi-only.
// R9/R10: slim unified k_L; OM folded through Wo (G), k_fbig K=1024.
// R11: position-permuted P12 columns.  R13: k_L A-reuse (32 MFMA/barrier).
// R14: BK=64 dual-slab for k_vt/k_fbig (32KB, 4 blocks/CU retained).
// R15: k_L reverted to R13 form (24KB, 4-block occupancy beats BK=64's
// barrier halving - measured 79.2us vs 83.0us).
// ---------------------------------------------------------------------------

typedef unsigned short u16;
typedef __attribute__((ext_vector_type(4))) float  f32x4;
typedef __attribute__((ext_vector_type(4))) u16    u16x4;
typedef __attribute__((ext_vector_type(8))) __bf16 bf16x8;

__device__ __forceinline__ float bf2f(u16 u) {
    return __uint_as_float(((unsigned)u) << 16);
}
__device__ __forceinline__ u16 f2bf(float f) {   // round-to-nearest-even
    unsigned u = __float_as_uint(f);
    u += 0x7fffu + ((u >> 16) & 1u);
    return (u16)(u >> 16);
}
__device__ __forceinline__ void gload16(const void* g, void* l) {
    __builtin_amdgcn_global_load_lds(
        (const __attribute__((address_space(1))) unsigned int*)g,
        (__attribute__((address_space(3))) unsigned int*)l, 16, 0, 0);
}

#define MASK_NONE 0x7fffffffu

// ---------------------------------------------------------------------------
// Generic MFMA GEMM core (m97-style 2-barrier loop, BK=32), 256 threads.
// (used by k_latT)
// ---------------------------------------------------------------------------
template<int BM, int BN, int WMW, int WNW>
__device__ __forceinline__ void gemm_core(
    const u16* __restrict__ A, int lda, unsigned amask, int koffA,
    const u16* __restrict__ Bm, int ldb, unsigned bmask, int koffB,
    int K, int trow, int tcol,
    u16* As, u16* Bs,
    f32x4 (&acc)[BM / WMW / 16][BN / WNW / 16])
{
    constexpr int FM = BM / WMW / 16;
    constexpr int FN = BN / WNW / 16;
    const int tid  = threadIdx.x;
    const int wid  = tid >> 6, lane = tid & 63;
    const int wm   = wid % WMW, wn = wid / WMW;
    const int wr   = wm * (BM / WMW), wc = wn * (BN / WNW);
    const int lrow = lane & 15, lk = (lane >> 4) * 8;

    for (int kt = 0; kt < K; kt += 32) {
        __syncthreads();
#pragma unroll
        for (int i = 0; i < BM / 64; i++) {           // stage A tile
            int c = i * 256 + tid;
            int row = c >> 2, kg = c & 3;
            unsigned kk = ((unsigned)(koffA + kt + kg * 8)) & amask;
            gload16(A + (size_t)(trow + row) * lda + kk, As + (size_t)c * 8);
        }
#pragma unroll
        for (int i = 0; i < BN / 64; i++) {           // stage B tile
            int c = i * 256 + tid;
            int col = c >> 2, kg = c & 3;
            unsigned kk = ((unsigned)(koffB + kt + kg * 8)) & bmask;
            gload16(Bm + (size_t)(tcol + col) * ldb + kk, Bs + (size_t)c * 8);
        }
        __syncthreads();

        bf16x8 af[FM], bfr[FN];
#pragma unroll
        for (int fm = 0; fm < FM; fm++)
            af[fm] = *(const bf16x8*)&As[(wr + fm * 16 + lrow) * 32 + lk];
#pragma unroll
        for (int fn = 0; fn < FN; fn++)
            bfr[fn] = *(const bf16x8*)&Bs[(wc + fn * 16 + lrow) * 32 + lk];
#pragma unroll
        for (int fm = 0; fm < FM; fm++)
#pragma unroll
            for (int fn = 0; fn < FN; fn++)
                acc[fm][fn] = __builtin_amdgcn_mfma_f32_16x16x32_bf16(
                    af[fm], bfr[fn], acc[fm][fn], 0, 0, 0);
    }
}

// ---------------------------------------------------------------------------
// BK=64 dual-slab GEMM core: one barrier pair per 64 K, two 32-wide slabs
// per operand (identical bank behavior to BK=32). As/Bs sized BM*64 / BN*64.
// ---------------------------------------------------------------------------
template<int BM, int BN, int WMW, int WNW>
__device__ __forceinline__ void gemm_core64(
    const u16* __restrict__ A, int lda,
    const u16* __restrict__ Bm, int ldb,
    int K, int trow, int tcol,
    u16* As, u16* Bs,
    f32x4 (&acc)[BM / WMW / 16][BN / WNW / 16])
{
    constexpr int FM = BM / WMW / 16;
    constexpr int FN = BN / WNW / 16;
    const int tid  = threadIdx.x;
    const int wid  = tid >> 6, lane = tid & 63;
    const int wm   = wid % WMW, wn = wid / WMW;
    const int wr   = wm * (BM / WMW), wc = wn * (BN / WNW);
    const int lrow = lane & 15, lk = (lane >> 4) * 8;

    for (int kt = 0; kt < K; kt += 64) {
        __syncthreads();
#pragma unroll
        for (int s = 0; s < 2; s++) {
#pragma unroll
            for (int i = 0; i < BM / 64; i++) {       // stage A slab s
                int c = i * 256 + tid;
                int row = c >> 2, kg = c & 3;
                gload16(A + (size_t)(trow + row) * lda + kt + s * 32 + kg * 8,
                        As + (size_t)s * BM * 32 + (size_t)c * 8);
            }
#pragma unroll
            for (int i = 0; i < BN / 64; i++) {       // stage B slab s
                int c = i * 256 + tid;
                int col = c >> 2, kg = c & 3;
                gload16(Bm + (size_t)(tcol + col) * ldb + kt + s * 32 + kg * 8,
                        Bs + (size_t)s * BN * 32 + (size_t)c * 8);
            }
        }
        __syncthreads();

#pragma unroll
        for (int s = 0; s < 2; s++) {
            bf16x8 af[FM], bfr[FN];
#pragma unroll
            for (int fm = 0; fm < FM; fm++)
                af[fm] = *(const bf16x8*)&As[s * BM * 32 + (wr + fm * 16 + lrow) * 32 + lk];
#pragma unroll
            for (int fn = 0; fn < FN; fn++)
                bfr[fn] = *(const bf16x8*)&Bs[s * BN * 32 + (wc + fn * 16 + lrow) * 32 + lk];
#pragma unroll
            for (int fm = 0; fm < FM; fm++)
#pragma unroll
                for (int fn = 0; fn < FN; fn++)
                    acc[fm][fn] = __builtin_amdgcn_mfma_f32_16x16x32_bf16(
                        af[fm], bfr[fn], acc[fm][fn], 0, 0, 0);
        }
    }
}

// ---------------------------------------------------------------------------
// Prep kernels (fp32 inputs)
// ---------------------------------------------------------------------------

// x -> xs = bf16(x) (hi only, row stride 512)
__global__ void prep_x(const float* __restrict__ x, u16* __restrict__ xs)
{
    int t = blockIdx.x * 256 + threadIdx.x;       // 2*16384*512/4
    int n = t >> 7, e4 = (t & 127) << 2;
    f32x4 v = *(const f32x4*)(x + (size_t)n * 512 + e4);
    u16x4 hi;
#pragma unroll
    for (int j = 0; j < 4; j++) hi[j] = f2bf(v[j]);
    *(u16x4*)(xs + (size_t)n * 512 + e4) = hi;
}

// which 0/1/2: CKF/CQF fp32, wV bf16 (composed with Wx).
__global__ void prep_w(const float* Wk, const float* Wcq, const float* Wv,
                       const float* Wx, float* CKF, float* CQF, u16* wV)
{
    int idx = blockIdx.x * 256 + threadIdx.x;     // 3*512*512
    int which = idx >> 18;
    int rem = idx & 262143;
    int c = rem >> 9, e = rem & 511;
    int h = c >> 6, d = c & 63;
    const float* W = which == 0 ? Wk : (which == 1 ? Wcq : Wv);
    float s = 0.f;
#pragma unroll 8
    for (int j = 0; j < 64; j++)
        s += W[d * 64 + j] * Wx[(h * 64 + j) * 512 + e];
    if (which == 0)      CKF[(size_t)c * 512 + e] = s;
    else if (which == 1) CQF[(size_t)c * 512 + e] = s;
    else                 wV [(size_t)c * 512 + e] = f2bf(s);
}

// Composed biases: biasKQ[0..511]=k-bias(h,d), [512..1023]=q-bias; biasV.
__global__ void prep_bias(const float* Wk, const float* Wcq, const float* Wv,
                          const float* bk, const float* bcq, const float* bv,
                          const float* bx, float* biasKQ, float* biasV)
{
    int t = blockIdx.x * 256 + threadIdx.x;       // 1536
    if (t < 1024) {
        const float* W  = (t < 512) ? Wk : Wcq;
        const float* bb = (t < 512) ? bk : bcq;
        int c = t & 511; int h = c >> 6, d = c & 63;
        float s = bb[d];
        for (int j = 0; j < 64; j++) s += W[d * 64 + j] * bx[h * 64 + j];
        biasKQ[t] = s;
    } else if (t < 1536) {
        int c = t - 1024; int h = c >> 6, d = c & 63;
        float s = bv[d];
        for (int j = 0; j < 64; j++) s += Wv[d * 64 + j] * bx[h * 64 + j];
        biasV[c] = s;
    }
}

// context: kc fp32 [bh][s][d]; vcT bf16 [bh][pos(s)][d] scaled (1-sigmoid).
// pos(s) = (s&15)*4 + (s>>4) matches k_L's permuted P12 column positions.
__global__ void prep_ctx(const float* ctx, const float* Wck, const float* bck,
                         const float* Wcv, const float* bcv, const float* smix,
                         float* kcf, u16* vcT)
{
    int t = blockIdx.x * 256 + threadIdx.x;       // 16*64*64
    int bh = t >> 12, r = t & 4095;
    int s_ = r >> 6, d = r & 63;
    const float* crow = ctx + ((size_t)bh * 64 + s_) * 64;
    float kc = bck[d], vc = bcv[d];
#pragma unroll 8
    for (int e = 0; e < 64; e++) {
        float ce = crow[e];
        kc += ce * Wck[d * 64 + e];
        vc += ce * Wcv[d * 64 + e];
    }
    kcf[(size_t)bh * 4096 + s_ * 64 + d] = kc;
    float w = 1.f / (1.f + __expf(-smix[0]));
    int pos = (s_ & 15) * 4 + (s_ >> 4);
    vcT[(size_t)bh * 4096 + pos * 64 + d] = f2bf((1.f - w) * vc);
}

// Merged: kg rows (BigB 0..511 [lo|hi], both b), kq rows (512+hs), CC consts.
__global__ void prep_b2(const float* CKF, const float* CQF, const float* qg,
                        const float* kcf, const float* biasKQ, u16* BigB, float* CC)
{
    int idx = blockIdx.x * 256 + threadIdx.x;     // 262144 + 524288 + 1536
    if (idx < 262144) {
        int hm = idx >> 9, e = idx & 511;
        int h = hm >> 6;
        float s = 0.f;
#pragma unroll 8
        for (int d = 0; d < 64; d++)
            s += CKF[(size_t)(h * 64 + d) * 512 + e] * qg[(size_t)hm * 64 + d];
        u16 hi = f2bf(s), lo = f2bf(s - bf2f(hi));
#pragma unroll
        for (int b = 0; b < 2; b++) {
            size_t base = (size_t)b * 1048576 + (size_t)hm * 1024;
            BigB[base + e]       = lo;
            BigB[base + 512 + e] = hi;
        }
    } else if (idx < 786432) {
        int i2 = idx - 262144;
        int r = i2 >> 9, e = i2 & 511;
        int b = r >> 9, hs = r & 511;
        int h = hs >> 6, s_ = hs & 63;
        float s = 0.f;
#pragma unroll 8
        for (int d = 0; d < 64; d++)
            s += CQF[(size_t)(h * 64 + d) * 512 + e]
               * kcf[(size_t)(b * 8 + h) * 4096 + s_ * 64 + d];
        u16 hi = f2bf(s), lo = f2bf(s - bf2f(hi));
        size_t base = (size_t)b * 1048576 + (size_t)(512 + hs) * 1024;
        BigB[base + e]       = lo;
        BigB[base + 512 + e] = hi;
    } else if (idx < 787968) {
        int t = idx - 786432;                     // 0..1535
        if (t < 512) {
            int h = t >> 6;
            float s = 0.f;
            for (int d = 0; d < 64; d++) s += biasKQ[h * 64 + d] * qg[(size_t)t * 64 + d];
            CC[t] = s; CC[1024 + t] = s;
        } else {
            int j = t - 512;
            int b = j >> 9, hs = j & 511;
            int h = hs >> 6, s_ = hs & 63;
            float s = 0.f;
            for (int d = 0; d < 64; d++)
                s += biasKQ[512 + h * 64 + d]
                   * kcf[(size_t)(b * 8 + h) * 4096 + s_ * 64 + d];
            CC[b * 1024 + 512 + hs] = s;
        }
    }
}

// vT = CV @ xs^T (+row bias): vT[b][hd][n]   (BK=64 core)
__global__ __launch_bounds__(256, 2) void k_vt(const u16* wV, const u16* xs,
                                               const float* biasV, u16* vT)
{
    __shared__ u16 As[128 * 64], Bs[128 * 64];
    f32x4 acc[4][4] = {};
    int b = blockIdx.z;
    int f = blockIdx.y * gridDim.x + blockIdx.x;       // 512 blocks per z
    int w = (f & 7) * 64 + (f >> 3);
    int trow = (w & 3) * 128;
    int tcol = (w >> 2) * 128;
    gemm_core64<128, 128, 2, 2>(wV, 512, xs + (size_t)b * 8388608, 512,
                                512, trow, tcol, As, Bs, acc);
    int tid = threadIdx.x, wid = tid >> 6, lane = tid & 63;
    int wr = (wid & 1) * 64, wc = (wid >> 1) * 64;
    int g = lane >> 4, li = lane & 15;
#pragma unroll
    for (int fm = 0; fm < 4; fm++)
#pragma unroll
        for (int fn = 0; fn < 4; fn++) {
            int col = tcol + wc + fn * 16 + li;
#pragma unroll
            for (int j = 0; j < 4; j++) {
                int a = trow + wr + fm * 16 + g * 4 + j;
                vT[((size_t)b * 512 + a) * 16384 + col] = f2bf(acc[fm][fn][j] + biasV[a]);
            }
        }
}

// ---------------------------------------------------------------------------
// k_L: ALL logit cols in one launch. 128n x 128cols per block, K=1024.
// R13 form: BigB rows are [lo(512)|hi(512)] against the SAME 512-wide x row,
// so the A-tile for k and k+512 is identical: stage A once per 32-K step,
// run 16 MFMA vs B-lo then 16 vs B-hi. 16 iters, 24KB LDS, 4 blocks/CU.
// P12 columns stored POSITION-PERMUTED within each 64-group:
//   position li*4+fn holds the prob of original col fn*16+li.
// ---------------------------------------------------------------------------
__global__ void k_L(const u16* xs, const u16* BigB, const float* CC,
                    u16* P12, float* DD)
{
    __shared__ u16 As[128 * 32], BsLo[128 * 32], BsHi[128 * 32];
    f32x4 acc[4][4] = {};
    int f = blockIdx.x;                  // 2048
    int w = (f & 7) * 256 + (f >> 3);    // XCD-chunked, bijective
    int jt = w & 7, nb = w >> 3;         // jt: col tile, nb: row tile
    int b = nb >> 7, ntile = nb & 127;
    int trow = ntile * 128, tcol = jt * 128;
    const u16* A  = xs   + (size_t)b * 8388608;
    const u16* Bm = BigB + (size_t)b * 1048576;
    int tid = threadIdx.x, wid = tid >> 6, lane = tid & 63;
    int wm = wid & 1, wn = wid >> 1;
    int wr = wm * 64, wc = wn * 64;
    int lrow = lane & 15, lk = (lane >> 4) * 8;

    for (int kt = 0; kt < 512; kt += 32) {
        __syncthreads();
#pragma unroll
        for (int i = 0; i < 2; i++) {                 // stage A once
            int c = i * 256 + tid;
            int row = c >> 2, kg = c & 3;
            gload16(A + (size_t)(trow + row) * 512 + kt + kg * 8, As + (size_t)c * 8);
        }
#pragma unroll
        for (int i = 0; i < 2; i++) {                 // stage B lo + hi
            int c = i * 256 + tid;
            int col = c >> 2, kg = c & 3;
            gload16(Bm + (size_t)(tcol + col) * 1024 + kt + kg * 8,
                    BsLo + (size_t)c * 8);
            gload16(Bm + (size_t)(tcol + col) * 1024 + 512 + kt + kg * 8,
                    BsHi + (size_t)c * 8);
        }
        __syncthreads();

        bf16x8 af[4], bfr[4];
#pragma unroll
        for (int fm = 0; fm < 4; fm++)
            af[fm] = *(const bf16x8*)&As[(wr + fm * 16 + lrow) * 32 + lk];
#pragma unroll
        for (int fn = 0; fn < 4; fn++)
            bfr[fn] = *(const bf16x8*)&BsLo[(wc + fn * 16 + lrow) * 32 + lk];
#pragma unroll
        for (int fm = 0; fm < 4; fm++)
#pragma unroll
            for (int fn = 0; fn < 4; fn++)
                acc[fm][fn] = __builtin_amdgcn_mfma_f32_16x16x32_bf16(
                    af[fm], bfr[fn], acc[fm][fn], 0, 0, 0);
#pragma unroll
        for (int fn = 0; fn < 4; fn++)
            bfr[fn] = *(const bf16x8*)&BsHi[(wc + fn * 16 + lrow) * 32 + lk];
#pragma unroll
        for (int fm = 0; fm < 4; fm++)
#pragma unroll
            for (int fn = 0; fn < 4; fn++)
                acc[fm][fn] = __builtin_amdgcn_mfma_f32_16x16x32_bf16(
                    af[fm], bfr[fn], acc[fm][fn], 0, 0, 0);
    }

    int g = lane >> 4, li = lane & 15;
    float cj[4];
#pragma unroll
    for (int fn = 0; fn < 4; fn++) cj[fn] = CC[b * 1024 + tcol + wc + fn * 16 + li];

    int h = jt * 2 + wn;                 // head index within dec half (jt<4)
#pragma unroll
    for (int fm = 0; fm < 4; fm++)
#pragma unroll
        for (int j = 0; j < 4; j++) {
            float ev[4]; float dsum = 0.f;
#pragma unroll
            for (int fn = 0; fn < 4; fn++) {
                ev[fn] = __expf(acc[fm][fn][j] + cj[fn]);
                dsum += ev[fn];
            }
            dsum += __shfl_xor(dsum, 1); dsum += __shfl_xor(dsum, 2);
            dsum += __shfl_xor(dsum, 4); dsum += __shfl_xor(dsum, 8);
            float inv = 1.f / dsum;
            int row = trow + wr + fm * 16 + g * 4 + j;
            size_t pb = ((size_t)b * 16384 + row) * 1024 + tcol + wc;
            u16x4 pk;
#pragma unroll
            for (int fn = 0; fn < 4; fn++) pk[fn] = f2bf(ev[fn] * inv);
            *(u16x4*)(P12 + pb + li * 4) = pk;
            if (jt < 4 && li == 0)
                DD[(size_t)(b * 8 + h) * 16384 + row] = dsum;
        }
}

// ---------------------------------------------------------------------------
// k_dene (coalesced): denp[(b,pos)][ch] = sum_{n in 128-row chunk} E[pos,n]
// ---------------------------------------------------------------------------
__global__ void k_dene(const u16* P12, const float* DD, float* denp)
{
    int blk = blockIdx.x;                 // 256 = b*128 + ch
    int b = blk >> 7, ch = blk & 127;
    int t = threadIdx.x;                  // 256: positions 2t, 2t+1
    int h = t >> 5;                       // (2t)>>6 == t>>5
    float s0 = 0.f, s1 = 0.f;
    const float* ddb = DD + (size_t)(b * 8 + h) * 16384;
    const u16* base = P12 + (size_t)b * 16384 * 1024 + 2 * t;
    int n0 = ch * 128;
    for (int i = 0; i < 128; i++) {
        int n = n0 + i;
        unsigned v = *(const unsigned*)(base + (size_t)n * 1024);
        float dd = ddb[n];
        s0 += bf2f((u16)(v & 0xffff)) * dd;
        s1 += bf2f((u16)(v >> 16)) * dd;
    }
    denp[(size_t)(b * 512 + 2 * t) * 128 + ch]     = s0;
    denp[(size_t)(b * 512 + 2 * t + 1) * 128 + ch] = s1;
}

// ---------------------------------------------------------------------------
// latT: latp[ch][bh][d][m] = sum_n vT[d][n] * (P12dec[n][h,m]*DD[n]) (split-K 32)
// ---------------------------------------------------------------------------
__global__ __launch_bounds__(256, 2) void k_latT(const u16* vT, const u16* P12,
                                                 const float* DD, float* latp)
{
    __shared__ u16 As[64 * 32], Bs[64 * 32];
    f32x4 acc[2][2] = {};
    int ch = blockIdx.x, bh = blockIdx.z;
    int b = bh >> 3, h = bh & 7;
    int koff = ch * 512;
    int tid = threadIdx.x, wid = tid >> 6, lane = tid & 63;
    int wr = (wid & 1) * 32, wc = (wid >> 1) * 32;
    int lrow = lane & 15, lk = (lane >> 4) * 8;
    const u16* Avt = vT + (size_t)bh * 64 * 16384;

    for (int kt = 0; kt < 512; kt += 32) {
        __syncthreads();
        {   // stage A: vT rows 64 x 32k
            int row = tid >> 2, kg = tid & 3;
            gload16(Avt + (size_t)row * 16384 + koff + kt + kg * 8, As + (size_t)tid * 8);
        }
        {   // stage B transposed: Bs[m][n], XOR-swizzled (n ^ ((m&3)<<3))
            int nl = tid & 31, m0 = (tid >> 5) * 8;
            int n = koff + kt + nl;
            const u16* src = P12 + ((size_t)b * 16384 + n) * 1024 + h * 64 + m0;
            u16x4 p0 = *(const u16x4*)src;
            u16x4 p1 = *(const u16x4*)(src + 4);
            float ddv = DD[(size_t)bh * 16384 + n];
#pragma unroll
            for (int i = 0; i < 4; i++) {
                int m = m0 + i;
                Bs[m * 32 + (nl ^ ((m & 3) << 3))] = f2bf(bf2f(p0[i]) * ddv);
            }
#pragma unroll
            for (int i = 0; i < 4; i++) {
                int m = m0 + 4 + i;
                Bs[m * 32 + (nl ^ ((m & 3) << 3))] = f2bf(bf2f(p1[i]) * ddv);
            }
        }
        __syncthreads();
        bf16x8 af[2], bfv[2];
#pragma unroll
        for (int fm = 0; fm < 2; fm++)
            af[fm] = *(const bf16x8*)&As[(wr + fm * 16 + lrow) * 32 + lk];
#pragma unroll
        for (int fn = 0; fn < 2; fn++) {
            int m = wc + fn * 16 + lrow;
            bfv[fn] = *(const bf16x8*)&Bs[m * 32 + (lk ^ ((m & 3) << 3))];
        }
#pragma unroll
        for (int fm = 0; fm < 2; fm++)
#pragma unroll
            for (int fn = 0; fn < 2; fn++)
                acc[fm][fn] = __builtin_amdgcn_mfma_f32_16x16x32_bf16(
                    af[fm], bfv[fn], acc[fm][fn], 0, 0, 0);
    }
    float* C = latp + ((size_t)ch * 16 + bh) * 4096;
    int g = lane >> 4, li = lane & 15;
#pragma unroll
    for (int fm = 0; fm < 2; fm++)
#pragma unroll
        for (int fn = 0; fn < 2; fn++)
#pragma unroll
            for (int j = 0; j < 4; j++) {
                int row = wr + fm * 16 + g * 4 + j;   // d
                int col = wc + fn * 16 + li;          // m
                C[row * 64 + col] = acc[fm][fn][j];
            }
}

// finish latent (+ inline den reduce): latB[bh][m][d] =
//   w * (sum_ch latp[d][m]) / (sum_c denp)    ([pos][d] layout for prep_g)
__global__ void k_latfin(const float* latp, const float* denp, const float* smix,
                         u16* latB)
{
    int t = blockIdx.x * 256 + threadIdx.x;       // 16*64*64
    int bh = t >> 12, r = t & 4095;
    int d = r >> 6, m = r & 63;
    int b = bh >> 3, h = bh & 7;
    float w = 1.f / (1.f + __expf(-smix[0]));
    float s = 0.f;
    for (int c = 0; c < 32; c++) s += latp[((size_t)c * 16 + bh) * 4096 + r];
    float dd = 0.f;
    const float* dp = denp + (size_t)(b * 512 + h * 64 + m) * 128;
    for (int c = 0; c < 128; c++) dd += dp[c];
    latB[(size_t)bh * 4096 + m * 64 + d] = f2bf(w * s / dd);
}

// ---------------------------------------------------------------------------
// prep_g: G[b][e][k] = sum_d (k<512 ? latB : vcT)[b,h(k)][k&63][d] * Wo[e][h*64+d]
// ---------------------------------------------------------------------------
__global__ void prep_g(const u16* latB, const u16* vcT, const float* Wo, u16* G)
{
    int idx = blockIdx.x * 256 + threadIdx.x;     // 2*512*1024
    int b = idx >> 19;
    int r = idx & 524287;
    int e = r >> 10, k = r & 1023;
    int h = (k >> 6) & 7, dm = k & 63;
    const u16* src = (k < 512) ? latB : vcT;
    const float* wrow = Wo + (size_t)e * 512 + h * 64;
    const u16* sb = src + (size_t)(b * 8 + h) * 4096 + dm * 64;
    float s = 0.f;
#pragma unroll
    for (int d0 = 0; d0 < 64; d0 += 4) {
        u16x4 sv = *(const u16x4*)(sb + d0);
        f32x4 wv = *(const f32x4*)(wrow + d0);
        s += bf2f(sv[0]) * wv[0] + bf2f(sv[1]) * wv[1]
           + bf2f(sv[2]) * wv[2] + bf2f(sv[3]) * wv[3];
    }
    G[(size_t)b * 524288 + (size_t)e * 1024 + k] = f2bf(s);
}

// ---------------------------------------------------------------------------
// k_fbig: out(fp32) = P12 @ G[b]^T + bo   (K=1024, BK=64 core)
// ---------------------------------------------------------------------------
__global__ __launch_bounds__(256, 2) void k_fbig(const u16* P12, const u16* G,
                                                 const float* bo, float* out)
{
    __shared__ u16 As[128 * 64], Bs[128 * 64];
    f32x4 acc[4][4] = {};
    int f = blockIdx.y * gridDim.x + blockIdx.x;       // 1024 blocks
    int w = (f & 7) * 128 + (f >> 3);
    int tcol = (w & 3) * 128, trow = (w >> 2) * 128;
    int b = trow >> 14;
    gemm_core64<128, 128, 2, 2>(P12, 1024, G + (size_t)b * 524288, 1024,
                                1024, trow, tcol, As, Bs, acc);
    int tid = threadIdx.x, wid = tid >> 6, lane = tid & 63;
    int wr = (wid & 1) * 64, wc = (wid >> 1) * 64;
    int g = lane >> 4, li = lane & 15;
#pragma unroll
    for (int fm = 0; fm < 4; fm++)
#pragma unroll
        for (int fn = 0; fn < 4; fn++) {
            int col = tcol + wc + fn * 16 + li;
            float bias = bo[col];
#pragma unroll
            for (int j = 0; j < 4; j++) {
                int row = trow + wr + fm * 16 + g * 4 + j;
                out[(size_t)row * 512 + col] = acc[fm][fn][j] + bias;
            }
        }
}

// ---------------------------------------------------------------------------
// Workspace layout (bytes), end ~154 MB (< proven-safe 209.7 MB). No aliases.
// ---------------------------------------------------------------------------
static const size_t XS_OFF   = 0;            // u16 32768x512    (33,554,432)
static const size_t P12_OFF  = 33554432;     // u16 2x16384x1024 (67,108,864)
static const size_t VT_OFF   = 100663296;    // u16 2x512x16384  (33,554,432)
static const size_t CKF_OFF  = 134217728;    // f32 512x512      (1,048,576)
static const size_t CQF_OFF  = 135266304;    // f32 512x512      (1,048,576)
static const size_t WV_OFF   = 136314880;    // u16 512x512      (524,288)
static const size_t BIGB_OFF = 136839168;    // u16 2x1024x1024  (4,194,304)
static const size_t KCF_OFF  = 141033472;    // f32 16x64x64     (262,144)
static const size_t VCT_OFF  = 141295616;    // u16 16x64x64     (131,072)
static const size_t BKQ_OFF  = 141426688;    // f32 1024         (4,096)
static const size_t BV_OFF   = 141430784;    // f32 512          (2,048)
static const size_t CC_OFF   = 141432832;    // f32 2048         (8,192)
static const size_t DENP_OFF = 141441024;    // f32 1024x128     (524,288)
static const size_t DD_OFF   = 141965312;    // f32 16x16384     (1,048,576)
static const size_t LATP_OFF = 143013888;    // f32 32x16x64x64  (8,388,608)
static const size_t LATB_OFF = 151402496;    // u16 16x64x64     (131,072)
static const size_t G_OFF    = 151533568;    // u16 2x512x1024   (2,097,152)
// end: 153,630,720

extern "C" void kernel_launch(void* const* d_in, const int* in_sizes, int n_in,
                              void* d_out, int out_size, void* d_ws, size_t ws_size,
                              hipStream_t stream)
{
    const float* x    = (const float*)d_in[0];
    const float* ctx  = (const float*)d_in[1];
    const float* qg   = (const float*)d_in[2];
    const float* Wx   = (const float*)d_in[3];
    const float* bx   = (const float*)d_in[4];
    const float* Wk   = (const float*)d_in[5];
    const float* bk   = (const float*)d_in[6];
    const float* Wv   = (const float*)d_in[7];
    const float* bv   = (const float*)d_in[8];
    const float* Wcq  = (const float*)d_in[9];
    const float* bcq  = (const float*)d_in[10];
    const float* Wck  = (const float*)d_in[11];
    const float* bck  = (const float*)d_in[12];
    const float* Wcv  = (const float*)d_in[13];
    const float* bcv  = (const float*)d_in[14];
    const float* smix = (const float*)d_in[15];
    const float* Wo   = (const float*)d_in[16];
    const float* bo   = (const float*)d_in[17];

    char* ws = (char*)d_ws;
    u16*   xs    = (u16*)  (ws + XS_OFF);
    u16*   P12   = (u16*)  (ws + P12_OFF);
    u16*   vT    = (u16*)  (ws + VT_OFF);
    float* CKF   = (float*)(ws + CKF_OFF);
    float* CQF   = (float*)(ws + CQF_OFF);
    u16*   wV    = (u16*)  (ws + WV_OFF);
    u16*   BigB  = (u16*)  (ws + BIGB_OFF);
    float* kcf   = (float*)(ws + KCF_OFF);
    u16*   vcT   = (u16*)  (ws + VCT_OFF);
    float* biasKQ= (float*)(ws + BKQ_OFF);
    float* biasV = (float*)(ws + BV_OFF);
    float* CC    = (float*)(ws + CC_OFF);
    float* denp  = (float*)(ws + DENP_OFF);
    float* DD    = (float*)(ws + DD_OFF);
    float* latp  = (float*)(ws + LATP_OFF);
    u16*   latB  = (u16*)  (ws + LATB_OFF);
    u16*   G     = (u16*)  (ws + G_OFF);

    prep_w   <<< 3072, 256, 0, stream>>>(Wk, Wcq, Wv, Wx, CKF, CQF, wV);
    prep_bias<<<    6, 256, 0, stream>>>(Wk, Wcq, Wv, bk, bcq, bv, bx, biasKQ, biasV);
    prep_ctx <<<  256, 256, 0, stream>>>(ctx, Wck, bck, Wcv, bcv, smix, kcf, vcT);
    prep_x   <<<16384, 256, 0, stream>>>(x, xs);
    prep_b2  <<< 3078, 256, 0, stream>>>(CKF, CQF, qg, kcf, biasKQ, BigB, CC);

    k_vt    <<<dim3(128,   4, 2), 256, 0, stream>>>(wV, xs, biasV, vT);
    k_L     <<<2048, 256, 0, stream>>>(xs, BigB, CC, P12, DD);
    k_dene  <<< 256, 256, 0, stream>>>(P12, DD, denp);
    k_latT  <<<dim3( 32,   1, 16), 256, 0, stream>>>(vT, P12, DD, latp);
    k_latfin<<< 256, 256, 0, stream>>>(latp, denp, smix, latB);
    prep_g  <<<4096, 256, 0, stream>>>(latB, vcT, Wo, G);
    k_fbig  <<<dim3(  4, 256, 1), 256, 0, stream>>>(P12, G, bo, (float*)d_out);
}

// Round 17
// 250.216 us; speedup vs baseline: 1.0631x; 1.0631x over previous
//
#include <hip/hip_runtime.h>

// ---------------------------------------------------------------------------
// GALE_FA: FLARE low-rank self-attn + context cross-attn + gated mix.
// R4: logits computed directly from x (k/q never materialized).
// R8: K-cut 1536->1024 (drop xl*Bhi), xs hi-only.
// R9/R10: slim unified k_L; OM folded through Wo (G), k_fbig K=1024.
// R11: position-permuted P12 columns.  R13: k_L A-reuse (32 MFMA/barrier).
// R14: BK=64 dual-slab for k_vt/k_fbig.  R15: k_L kept at R13 form.
// R16: dene fused into k_latT staging (k_dene deleted); 4 input preps merged
// into prep_all (12 -> 8 launches). GEMM kernels byte-identical to R15.
// ---------------------------------------------------------------------------

typedef unsigned short u16;
typedef __attribute__((ext_vector_type(4))) float  f32x4;
typedef __attribute__((ext_vector_type(4))) u16    u16x4;
typedef __attribute__((ext_vector_type(8))) __bf16 bf16x8;

__device__ __forceinline__ float bf2f(u16 u) {
    return __uint_as_float(((unsigned)u) << 16);
}
__device__ __forceinline__ u16 f2bf(float f) {   // round-to-nearest-even
    unsigned u = __float_as_uint(f);
    u += 0x7fffu + ((u >> 16) & 1u);
    return (u16)(u >> 16);
}
__device__ __forceinline__ void gload16(const void* g, void* l) {
    __builtin_amdgcn_global_load_lds(
        (const __attribute__((address_space(1))) unsigned int*)g,
        (__attribute__((address_space(3))) unsigned int*)l, 16, 0, 0);
}

#define MASK_NONE 0x7fffffffu

// ---------------------------------------------------------------------------
// BK=64 dual-slab GEMM core (k_vt / k_fbig): one barrier pair per 64 K.
// ---------------------------------------------------------------------------
template<int BM, int BN, int WMW, int WNW>
__device__ __forceinline__ void gemm_core64(
    const u16* __restrict__ A, int lda,
    const u16* __restrict__ Bm, int ldb,
    int K, int trow, int tcol,
    u16* As, u16* Bs,
    f32x4 (&acc)[BM / WMW / 16][BN / WNW / 16])
{
    constexpr int FM = BM / WMW / 16;
    constexpr int FN = BN / WNW / 16;
    const int tid  = threadIdx.x;
    const int wid  = tid >> 6, lane = tid & 63;
    const int wm   = wid % WMW, wn = wid / WMW;
    const int wr   = wm * (BM / WMW), wc = wn * (BN / WNW);
    const int lrow = lane & 15, lk = (lane >> 4) * 8;

    for (int kt = 0; kt < K; kt += 64) {
        __syncthreads();
#pragma unroll
        for (int s = 0; s < 2; s++) {
#pragma unroll
            for (int i = 0; i < BM / 64; i++) {       // stage A slab s
                int c = i * 256 + tid;
                int row = c >> 2, kg = c & 3;
                gload16(A + (size_t)(trow + row) * lda + kt + s * 32 + kg * 8,
                        As + (size_t)s * BM * 32 + (size_t)c * 8);
            }
#pragma unroll
            for (int i = 0; i < BN / 64; i++) {       // stage B slab s
                int c = i * 256 + tid;
                int col = c >> 2, kg = c & 3;
                gload16(Bm + (size_t)(tcol + col) * ldb + kt + s * 32 + kg * 8,
                        Bs + (size_t)s * BN * 32 + (size_t)c * 8);
            }
        }
        __syncthreads();

#pragma unroll
        for (int s = 0; s < 2; s++) {
            bf16x8 af[FM], bfr[FN];
#pragma unroll
            for (int fm = 0; fm < FM; fm++)
                af[fm] = *(const bf16x8*)&As[s * BM * 32 + (wr + fm * 16 + lrow) * 32 + lk];
#pragma unroll
            for (int fn = 0; fn < FN; fn++)
                bfr[fn] = *(const bf16x8*)&Bs[s * BN * 32 + (wc + fn * 16 + lrow) * 32 + lk];
#pragma unroll
            for (int fm = 0; fm < FM; fm++)
#pragma unroll
                for (int fn = 0; fn < FN; fn++)
                    acc[fm][fn] = __builtin_amdgcn_mfma_f32_16x16x32_bf16(
                        af[fm], bfr[fn], acc[fm][fn], 0, 0, 0);
        }
    }
}

// ---------------------------------------------------------------------------
// prep_all: merged independent input preps (block-range dispatch).
//   blocks [0,16384)        prep_x : x -> xs bf16 hi
//   blocks [16384,19456)    prep_w : CKF/CQF fp32, wV bf16
//   blocks [19456,19712)    prep_ctx: kc fp32; vcT bf16 [bh][pos(s)][d]
//   blocks [19712,19718)    prep_bias: biasKQ / biasV
// ---------------------------------------------------------------------------
__global__ void prep_all(const float* x, const float* Wk, const float* Wcq,
                         const float* Wv, const float* Wx,
                         const float* bk, const float* bcq, const float* bv,
                         const float* bx,
                         const float* ctx, const float* Wck, const float* bck,
                         const float* Wcv, const float* bcv, const float* smix,
                         u16* xs, float* CKF, float* CQF, u16* wV,
                         float* biasKQ, float* biasV, float* kcf, u16* vcT)
{
    int blk = blockIdx.x;
    if (blk < 16384) {                       // ---- prep_x ----
        int t = blk * 256 + threadIdx.x;     // 2*16384*512/4
        int n = t >> 7, e4 = (t & 127) << 2;
        f32x4 v = *(const f32x4*)(x + (size_t)n * 512 + e4);
        u16x4 hi;
#pragma unroll
        for (int j = 0; j < 4; j++) hi[j] = f2bf(v[j]);
        *(u16x4*)(xs + (size_t)n * 512 + e4) = hi;
    } else if (blk < 19456) {                // ---- prep_w ----
        int idx = (blk - 16384) * 256 + threadIdx.x;  // 3*512*512
        int which = idx >> 18;
        int rem = idx & 262143;
        int c = rem >> 9, e = rem & 511;
        int h = c >> 6, d = c & 63;
        const float* W = which == 0 ? Wk : (which == 1 ? Wcq : Wv);
        float s = 0.f;
#pragma unroll 8
        for (int j = 0; j < 64; j++)
            s += W[d * 64 + j] * Wx[(h * 64 + j) * 512 + e];
        if (which == 0)      CKF[(size_t)c * 512 + e] = s;
        else if (which == 1) CQF[(size_t)c * 512 + e] = s;
        else                 wV [(size_t)c * 512 + e] = f2bf(s);
    } else if (blk < 19712) {                // ---- prep_ctx ----
        int t = (blk - 19456) * 256 + threadIdx.x;    // 16*64*64
        int bh = t >> 12, r = t & 4095;
        int s_ = r >> 6, d = r & 63;
        const float* crow = ctx + ((size_t)bh * 64 + s_) * 64;
        float kc = bck[d], vc = bcv[d];
#pragma unroll 8
        for (int e = 0; e < 64; e++) {
            float ce = crow[e];
            kc += ce * Wck[d * 64 + e];
            vc += ce * Wcv[d * 64 + e];
        }
        kcf[(size_t)bh * 4096 + s_ * 64 + d] = kc;
        float w = 1.f / (1.f + __expf(-smix[0]));
        int pos = (s_ & 15) * 4 + (s_ >> 4);
        vcT[(size_t)bh * 4096 + pos * 64 + d] = f2bf((1.f - w) * vc);
    } else {                                 // ---- prep_bias ----
        int t = (blk - 19712) * 256 + threadIdx.x;    // 1536
        if (t < 1024) {
            const float* W  = (t < 512) ? Wk : Wcq;
            const float* bb = (t < 512) ? bk : bcq;
            int c = t & 511; int h = c >> 6, d = c & 63;
            float s = bb[d];
            for (int j = 0; j < 64; j++) s += W[d * 64 + j] * bx[h * 64 + j];
            biasKQ[t] = s;
        } else if (t < 1536) {
            int c = t - 1024; int h = c >> 6, d = c & 63;
            float s = bv[d];
            for (int j = 0; j < 64; j++) s += Wv[d * 64 + j] * bx[h * 64 + j];
            biasV[c] = s;
        }
    }
}

// Merged: kg rows (BigB 0..511 [lo|hi], both b), kq rows (512+hs), CC consts.
__global__ void prep_b2(const float* CKF, const float* CQF, const float* qg,
                        const float* kcf, const float* biasKQ, u16* BigB, float* CC)
{
    int idx = blockIdx.x * 256 + threadIdx.x;     // 262144 + 524288 + 1536
    if (idx < 262144) {
        int hm = idx >> 9, e = idx & 511;
        int h = hm >> 6;
        float s = 0.f;
#pragma unroll 8
        for (int d = 0; d < 64; d++)
            s += CKF[(size_t)(h * 64 + d) * 512 + e] * qg[(size_t)hm * 64 + d];
        u16 hi = f2bf(s), lo = f2bf(s - bf2f(hi));
#pragma unroll
        for (int b = 0; b < 2; b++) {
            size_t base = (size_t)b * 1048576 + (size_t)hm * 1024;
            BigB[base + e]       = lo;
            BigB[base + 512 + e] = hi;
        }
    } else if (idx < 786432) {
        int i2 = idx - 262144;
        int r = i2 >> 9, e = i2 & 511;
        int b = r >> 9, hs = r & 511;
        int h = hs >> 6, s_ = hs & 63;
        float s = 0.f;
#pragma unroll 8
        for (int d = 0; d < 64; d++)
            s += CQF[(size_t)(h * 64 + d) * 512 + e]
               * kcf[(size_t)(b * 8 + h) * 4096 + s_ * 64 + d];
        u16 hi = f2bf(s), lo = f2bf(s - bf2f(hi));
        size_t base = (size_t)b * 1048576 + (size_t)(512 + hs) * 1024;
        BigB[base + e]       = lo;
        BigB[base + 512 + e] = hi;
    } else if (idx < 787968) {
        int t = idx - 786432;                     // 0..1535
        if (t < 512) {
            int h = t >> 6;
            float s = 0.f;
            for (int d = 0; d < 64; d++) s += biasKQ[h * 64 + d] * qg[(size_t)t * 64 + d];
            CC[t] = s; CC[1024 + t] = s;
        } else {
            int j = t - 512;
            int b = j >> 9, hs = j & 511;
            int h = hs >> 6, s_ = hs & 63;
            float s = 0.f;
            for (int d = 0; d < 64; d++)
                s += biasKQ[512 + h * 64 + d]
                   * kcf[(size_t)(b * 8 + h) * 4096 + s_ * 64 + d];
            CC[b * 1024 + 512 + hs] = s;
        }
    }
}

// vT = CV @ xs^T (+row bias): vT[b][hd][n]   (BK=64 core)
__global__ __launch_bounds__(256, 2) void k_vt(const u16* wV, const u16* xs,
                                               const float* biasV, u16* vT)
{
    __shared__ u16 As[128 * 64], Bs[128 * 64];
    f32x4 acc[4][4] = {};
    int b = blockIdx.z;
    int f = blockIdx.y * gridDim.x + blockIdx.x;       // 512 blocks per z
    int w = (f & 7) * 64 + (f >> 3);
    int trow = (w & 3) * 128;
    int tcol = (w >> 2) * 128;
    gemm_core64<128, 128, 2, 2>(wV, 512, xs + (size_t)b * 8388608, 512,
                                512, trow, tcol, As, Bs, acc);
    int tid = threadIdx.x, wid = tid >> 6, lane = tid & 63;
    int wr = (wid & 1) * 64, wc = (wid >> 1) * 64;
    int g = lane >> 4, li = lane & 15;
#pragma unroll
    for (int fm = 0; fm < 4; fm++)
#pragma unroll
        for (int fn = 0; fn < 4; fn++) {
            int col = tcol + wc + fn * 16 + li;
#pragma unroll
            for (int j = 0; j < 4; j++) {
                int a = trow + wr + fm * 16 + g * 4 + j;
                vT[((size_t)b * 512 + a) * 16384 + col] = f2bf(acc[fm][fn][j] + biasV[a]);
            }
        }
}

// ---------------------------------------------------------------------------
// k_L: ALL logit cols in one launch. 128n x 128cols per block, K=1024.
// R13 form: A-tile staged once per 32-K step, reused for BigB lo and hi
// halves. 16 iters, 24KB LDS, 4 blocks/CU.  P12 columns POSITION-PERMUTED:
// position li*4+fn holds the prob of original col fn*16+li.
// ---------------------------------------------------------------------------
__global__ void k_L(const u16* xs, const u16* BigB, const float* CC,
                    u16* P12, float* DD)
{
    __shared__ u16 As[128 * 32], BsLo[128 * 32], BsHi[128 * 32];
    f32x4 acc[4][4] = {};
    int f = blockIdx.x;                  // 2048
    int w = (f & 7) * 256 + (f >> 3);    // XCD-chunked, bijective
    int jt = w & 7, nb = w >> 3;         // jt: col tile, nb: row tile
    int b = nb >> 7, ntile = nb & 127;
    int trow = ntile * 128, tcol = jt * 128;
    const u16* A  = xs   + (size_t)b * 8388608;
    const u16* Bm = BigB + (size_t)b * 1048576;
    int tid = threadIdx.x, wid = tid >> 6, lane = tid & 63;
    int wm = wid & 1, wn = wid >> 1;
    int wr = wm * 64, wc = wn * 64;
    int lrow = lane & 15, lk = (lane >> 4) * 8;

    for (int kt = 0; kt < 512; kt += 32) {
        __syncthreads();
#pragma unroll
        for (int i = 0; i < 2; i++) {                 // stage A once
            int c = i * 256 + tid;
            int row = c >> 2, kg = c & 3;
            gload16(A + (size_t)(trow + row) * 512 + kt + kg * 8, As + (size_t)c * 8);
        }
#pragma unroll
        for (int i = 0; i < 2; i++) {                 // stage B lo + hi
            int c = i * 256 + tid;
            int col = c >> 2, kg = c & 3;
            gload16(Bm + (size_t)(tcol + col) * 1024 + kt + kg * 8,
                    BsLo + (size_t)c * 8);
            gload16(Bm + (size_t)(tcol + col) * 1024 + 512 + kt + kg * 8,
                    BsHi + (size_t)c * 8);
        }
        __syncthreads();

        bf16x8 af[4], bfr[4];
#pragma unroll
        for (int fm = 0; fm < 4; fm++)
            af[fm] = *(const bf16x8*)&As[(wr + fm * 16 + lrow) * 32 + lk];
#pragma unroll
        for (int fn = 0; fn < 4; fn++)
            bfr[fn] = *(const bf16x8*)&BsLo[(wc + fn * 16 + lrow) * 32 + lk];
#pragma unroll
        for (int fm = 0; fm < 4; fm++)
#pragma unroll
            for (int fn = 0; fn < 4; fn++)
                acc[fm][fn] = __builtin_amdgcn_mfma_f32_16x16x32_bf16(
                    af[fm], bfr[fn], acc[fm][fn], 0, 0, 0);
#pragma unroll
        for (int fn = 0; fn < 4; fn++)
            bfr[fn] = *(const bf16x8*)&BsHi[(wc + fn * 16 + lrow) * 32 + lk];
#pragma unroll
        for (int fm = 0; fm < 4; fm++)
#pragma unroll
            for (int fn = 0; fn < 4; fn++)
                acc[fm][fn] = __builtin_amdgcn_mfma_f32_16x16x32_bf16(
                    af[fm], bfr[fn], acc[fm][fn], 0, 0, 0);
    }

    int g = lane >> 4, li = lane & 15;
    float cj[4];
#pragma unroll
    for (int fn = 0; fn < 4; fn++) cj[fn] = CC[b * 1024 + tcol + wc + fn * 16 + li];

    int h = jt * 2 + wn;                 // head index within dec half (jt<4)
#pragma unroll
    for (int fm = 0; fm < 4; fm++)
#pragma unroll
        for (int j = 0; j < 4; j++) {
            float ev[4]; float dsum = 0.f;
#pragma unroll
            for (int fn = 0; fn < 4; fn++) {
                ev[fn] = __expf(acc[fm][fn][j] + cj[fn]);
                dsum += ev[fn];
            }
            dsum += __shfl_xor(dsum, 1); dsum += __shfl_xor(dsum, 2);
            dsum += __shfl_xor(dsum, 4); dsum += __shfl_xor(dsum, 8);
            float inv = 1.f / dsum;
            int row = trow + wr + fm * 16 + g * 4 + j;
            size_t pb = ((size_t)b * 16384 + row) * 1024 + tcol + wc;
            u16x4 pk;
#pragma unroll
            for (int fn = 0; fn < 4; fn++) pk[fn] = f2bf(ev[fn] * inv);
            *(u16x4*)(P12 + pb + li * 4) = pk;
            if (jt < 4 && li == 0)
                DD[(size_t)(b * 8 + h) * 16384 + row] = dsum;
        }
}

// ---------------------------------------------------------------------------
// latT (+ fused dene): latp[ch][bh][d][m] = sum_n vT[d][n]*(P12dec[n][h,m]*DD[n])
// (split-K 32).  The staging values v = P*DD (f32, pre-rounding) are also
// accumulated into dacc[8] and reduced to denp[(bh*64+m)][ch] at the end.
// ---------------------------------------------------------------------------
__global__ __launch_bounds__(256, 2) void k_latT(const u16* vT, const u16* P12,
                                                 const float* DD, float* latp,
                                                 float* denp)
{
    __shared__ u16 sh2[4096];            // As[2048] | Bs[2048]; reduce as f32[2048]
    u16* As = sh2;
    u16* Bs = sh2 + 2048;
    f32x4 acc[2][2] = {};
    float dacc[8] = {0.f, 0.f, 0.f, 0.f, 0.f, 0.f, 0.f, 0.f};
    int ch = blockIdx.x, bh = blockIdx.z;
    int b = bh >> 3, h = bh & 7;
    int koff = ch * 512;
    int tid = threadIdx.x, wid = tid >> 6, lane = tid & 63;
    int wr = (wid & 1) * 32, wc = (wid >> 1) * 32;
    int lrow = lane & 15, lk = (lane >> 4) * 8;
    const u16* Avt = vT + (size_t)bh * 64 * 16384;
    int nl = tid & 31, m0 = (tid >> 5) * 8;

    for (int kt = 0; kt < 512; kt += 32) {
        __syncthreads();
        {   // stage A: vT rows 64 x 32k
            int row = tid >> 2, kg = tid & 3;
            gload16(Avt + (size_t)row * 16384 + koff + kt + kg * 8, As + (size_t)tid * 8);
        }
        {   // stage B transposed: Bs[m][n], XOR-swizzled; accumulate dene
            int n = koff + kt + nl;
            const u16* src = P12 + ((size_t)b * 16384 + n) * 1024 + h * 64 + m0;
            u16x4 p0 = *(const u16x4*)src;
            u16x4 p1 = *(const u16x4*)(src + 4);
            float ddv = DD[(size_t)bh * 16384 + n];
#pragma unroll
            for (int i = 0; i < 4; i++) {
                int m = m0 + i;
                float v = bf2f(p0[i]) * ddv;
                dacc[i] += v;
                Bs[m * 32 + (nl ^ ((m & 3) << 3))] = f2bf(v);
            }
#pragma unroll
            for (int i = 0; i < 4; i++) {
                int m = m0 + 4 + i;
                float v = bf2f(p1[i]) * ddv;
                dacc[4 + i] += v;
                Bs[m * 32 + (nl ^ ((m & 3) << 3))] = f2bf(v);
            }
        }
        __syncthreads();
        bf16x8 af[2], bfv[2];
#pragma unroll
        for (int fm = 0; fm < 2; fm++)
            af[fm] = *(const bf16x8*)&As[(wr + fm * 16 + lrow) * 32 + lk];
#pragma unroll
        for (int fn = 0; fn < 2; fn++) {
            int m = wc + fn * 16 + lrow;
            bfv[fn] = *(const bf16x8*)&Bs[m * 32 + (lk ^ ((m & 3) << 3))];
        }
#pragma unroll
        for (int fm = 0; fm < 2; fm++)
#pragma unroll
            for (int fn = 0; fn < 2; fn++)
                acc[fm][fn] = __builtin_amdgcn_mfma_f32_16x16x32_bf16(
                    af[fm], bfv[fn], acc[fm][fn], 0, 0, 0);
    }
    float* C = latp + ((size_t)ch * 16 + bh) * 4096;
    int g = lane >> 4, li = lane & 15;
#pragma unroll
    for (int fm = 0; fm < 2; fm++)
#pragma unroll
        for (int fn = 0; fn < 2; fn++)
#pragma unroll
            for (int j = 0; j < 4; j++) {
                int row = wr + fm * 16 + g * 4 + j;   // d
                int col = wc + fn * 16 + li;          // m
                C[row * 64 + col] = acc[fm][fn][j];
            }
    // dene reduce: red[m][nl] = dacc; 64 rows sum 32 partials -> denp.
    __syncthreads();                     // all waves done reading As/Bs
    float* red = (float*)sh2;            // 2048 f32 = 8KB
#pragma unroll
    for (int i = 0; i < 8; i++)
        red[(m0 + i) * 32 + nl] = dacc[i];
    __syncthreads();
    if (tid < 64) {
        float s = 0.f;
        const float* rr = red + tid * 32;
        for (int j = 0; j < 32; j++) s += rr[j];
        denp[(size_t)(bh * 64 + tid) * 32 + ch] = s;
    }
}

// finish latent (+ inline den reduce): latB[bh][m][d] =
//   w * (sum_ch latp[d][m]) / (sum_c denp)    ([pos][d] layout for prep_g)
__global__ void k_latfin(const float* latp, const float* denp, const float* smix,
                         u16* latB)
{
    int t = blockIdx.x * 256 + threadIdx.x;       // 16*64*64
    int bh = t >> 12, r = t & 4095;
    int d = r >> 6, m = r & 63;
    float w = 1.f / (1.f + __expf(-smix[0]));
    float s = 0.f;
    for (int c = 0; c < 32; c++) s += latp[((size_t)c * 16 + bh) * 4096 + r];
    float dd = 0.f;
    const float* dp = denp + (size_t)(bh * 64 + m) * 32;
    for (int c = 0; c < 32; c++) dd += dp[c];
    latB[(size_t)bh * 4096 + m * 64 + d] = f2bf(w * s / dd);
}

// ---------------------------------------------------------------------------
// prep_g: G[b][e][k] = sum_d (k<512 ? latB : vcT)[b,h(k)][k&63][d] * Wo[e][h*64+d]
// ---------------------------------------------------------------------------
__global__ void prep_g(const u16* latB, const u16* vcT, const float* Wo, u16* G)
{
    int idx = blockIdx.x * 256 + threadIdx.x;     // 2*512*1024
    int b = idx >> 19;
    int r = idx & 524287;
    int e = r >> 10, k = r & 1023;
    int h = (k >> 6) & 7, dm = k & 63;
    const u16* src = (k < 512) ? latB : vcT;
    const float* wrow = Wo + (size_t)e * 512 + h * 64;
    const u16* sb = src + (size_t)(b * 8 + h) * 4096 + dm * 64;
    float s = 0.f;
#pragma unroll
    for (int d0 = 0; d0 < 64; d0 += 4) {
        u16x4 sv = *(const u16x4*)(sb + d0);
        f32x4 wv = *(const f32x4*)(wrow + d0);
        s += bf2f(sv[0]) * wv[0] + bf2f(sv[1]) * wv[1]
           + bf2f(sv[2]) * wv[2] + bf2f(sv[3]) * wv[3];
    }
    G[(size_t)b * 524288 + (size_t)e * 1024 + k] = f2bf(s);
}

// ---------------------------------------------------------------------------
// k_fbig: out(fp32) = P12 @ G[b]^T + bo   (K=1024, BK=64 core)
// ---------------------------------------------------------------------------
__global__ __launch_bounds__(256, 2) void k_fbig(const u16* P12, const u16* G,
                                                 const float* bo, float* out)
{
    __shared__ u16 As[128 * 64], Bs[128 * 64];
    f32x4 acc[4][4] = {};
    int f = blockIdx.y * gridDim.x + blockIdx.x;       // 1024 blocks
    int w = (f & 7) * 128 + (f >> 3);
    int tcol = (w & 3) * 128, trow = (w >> 2) * 128;
    int b = trow >> 14;
    gemm_core64<128, 128, 2, 2>(P12, 1024, G + (size_t)b * 524288, 1024,
                                1024, trow, tcol, As, Bs, acc);
    int tid = threadIdx.x, wid = tid >> 6, lane = tid & 63;
    int wr = (wid & 1) * 64, wc = (wid >> 1) * 64;
    int g = lane >> 4, li = lane & 15;
#pragma unroll
    for (int fm = 0; fm < 4; fm++)
#pragma unroll
        for (int fn = 0; fn < 4; fn++) {
            int col = tcol + wc + fn * 16 + li;
            float bias = bo[col];
#pragma unroll
            for (int j = 0; j < 4; j++) {
                int row = trow + wr + fm * 16 + g * 4 + j;
                out[(size_t)row * 512 + col] = acc[fm][fn][j] + bias;
            }
        }
}

// ---------------------------------------------------------------------------
// Workspace layout (bytes), end ~154 MB (< proven-safe 209.7 MB). No aliases.
// ---------------------------------------------------------------------------
static const size_t XS_OFF   = 0;            // u16 32768x512    (33,554,432)
static const size_t P12_OFF  = 33554432;     // u16 2x16384x1024 (67,108,864)
static const size_t VT_OFF   = 100663296;    // u16 2x512x16384  (33,554,432)
static const size_t CKF_OFF  = 134217728;    // f32 512x512      (1,048,576)
static const size_t CQF_OFF  = 135266304;    // f32 512x512      (1,048,576)
static const size_t WV_OFF   = 136314880;    // u16 512x512      (524,288)
static const size_t BIGB_OFF = 136839168;    // u16 2x1024x1024  (4,194,304)
static const size_t KCF_OFF  = 141033472;    // f32 16x64x64     (262,144)
static const size_t VCT_OFF  = 141295616;    // u16 16x64x64     (131,072)
static const size_t BKQ_OFF  = 141426688;    // f32 1024         (4,096)
static const size_t BV_OFF   = 141430784;    // f32 512          (2,048)
static const size_t CC_OFF   = 141432832;    // f32 2048         (8,192)
static const size_t DENP_OFF = 141441024;    // f32 1024x32      (131,072)
static const size_t DD_OFF   = 141965312;    // f32 16x16384     (1,048,576)
static const size_t LATP_OFF = 143013888;    // f32 32x16x64x64  (8,388,608)
static const size_t LATB_OFF = 151402496;    // u16 16x64x64     (131,072)
static const size_t G_OFF    = 151533568;    // u16 2x512x1024   (2,097,152)
// end: 153,630,720

extern "C" void kernel_launch(void* const* d_in, const int* in_sizes, int n_in,
                              void* d_out, int out_size, void* d_ws, size_t ws_size,
                              hipStream_t stream)
{
    const float* x    = (const float*)d_in[0];
    const float* ctx  = (const float*)d_in[1];
    const float* qg   = (const float*)d_in[2];
    const float* Wx   = (const float*)d_in[3];
    const float* bx   = (const float*)d_in[4];
    const float* Wk   = (const float*)d_in[5];
    const float* bk   = (const float*)d_in[6];
    const float* Wv   = (const float*)d_in[7];
    const float* bv   = (const float*)d_in[8];
    const float* Wcq  = (const float*)d_in[9];
    const float* bcq  = (const float*)d_in[10];
    const float* Wck  = (const float*)d_in[11];
    const float* bck  = (const float*)d_in[12];
    const float* Wcv  = (const float*)d_in[13];
    const float* bcv  = (const float*)d_in[14];
    const float* smix = (const float*)d_in[15];
    const float* Wo   = (const float*)d_in[16];
    const float* bo   = (const float*)d_in[17];

    char* ws = (char*)d_ws;
    u16*   xs    = (u16*)  (ws + XS_OFF);
    u16*   P12   = (u16*)  (ws + P12_OFF);
    u16*   vT    = (u16*)  (ws + VT_OFF);
    float* CKF   = (float*)(ws + CKF_OFF);
    float* CQF   = (float*)(ws + CQF_OFF);
    u16*   wV    = (u16*)  (ws + WV_OFF);
    u16*   BigB  = (u16*)  (ws + BIGB_OFF);
    float* kcf   = (float*)(ws + KCF_OFF);
    u16*   vcT   = (u16*)  (ws + VCT_OFF);
    float* biasKQ= (float*)(ws + BKQ_OFF);
    float* biasV = (float*)(ws + BV_OFF);
    float* CC    = (float*)(ws + CC_OFF);
    float* denp  = (float*)(ws + DENP_OFF);
    float* DD    = (float*)(ws + DD_OFF);
    float* latp  = (float*)(ws + LATP_OFF);
    u16*   latB  = (u16*)  (ws + LATB_OFF);
    u16*   G     = (u16*)  (ws + G_OFF);

    prep_all<<<19718, 256, 0, stream>>>(x, Wk, Wcq, Wv, Wx, bk, bcq, bv, bx,
                                        ctx, Wck, bck, Wcv, bcv, smix,
                                        xs, CKF, CQF, wV, biasKQ, biasV, kcf, vcT);
    prep_b2 <<< 3078, 256, 0, stream>>>(CKF, CQF, qg, kcf, biasKQ, BigB, CC);

    k_vt    <<<dim3(128,   4, 2), 256, 0, stream>>>(wV, xs, biasV, vT);
    k_L     <<<2048, 256, 0, stream>>>(xs, BigB, CC, P12, DD);
    k_latT  <<<dim3( 32,   1, 16), 256, 0, stream>>>(vT, P12, DD, latp, denp);
    k_latfin<<< 256, 256, 0, stream>>>(latp, denp, smix, latB);
    prep_g  <<<4096, 256, 0, stream>>>(latB, vcT, Wo, G);
    k_fbig  <<<dim3(  4, 256, 1), 256, 0, stream>>>(P12, G, bo, (float*)d_out);
}

// Round 18
// 243.374 us; speedup vs baseline: 1.0930x; 1.0281x over previous
//
#include <hip/hip_runtime.h>

// ---------------------------------------------------------------------------
// GALE_FA: FLARE low-rank self-attn + context cross-attn + gated mix.
// R4: logits computed directly from x (k/q never materialized).
// R8: K-cut 1536->1024 (drop xl*Bhi), xs hi-only.
// R9/R10: slim unified k_L; OM folded through Wo (G), k_fbig K=1024.
// R11: position-permuted P12 columns.  R13: k_L A-reuse (32 MFMA/barrier).
// R14: BK=64 dual-slab for k_vt/k_fbig.  R16: dene fused into k_latT,
// prep_all merged.  R17: k_vt merged into k_L (block-range dispatch, shared
// 32KB LDS union; k_L blocks first, k_vt blocks fill the tail). 7 launches.
// ---------------------------------------------------------------------------

typedef unsigned short u16;
typedef __attribute__((ext_vector_type(4))) float  f32x4;
typedef __attribute__((ext_vector_type(4))) u16    u16x4;
typedef __attribute__((ext_vector_type(8))) __bf16 bf16x8;

__device__ __forceinline__ float bf2f(u16 u) {
    return __uint_as_float(((unsigned)u) << 16);
}
__device__ __forceinline__ u16 f2bf(float f) {   // round-to-nearest-even
    unsigned u = __float_as_uint(f);
    u += 0x7fffu + ((u >> 16) & 1u);
    return (u16)(u >> 16);
}
__device__ __forceinline__ void gload16(const void* g, void* l) {
    __builtin_amdgcn_global_load_lds(
        (const __attribute__((address_space(1))) unsigned int*)g,
        (__attribute__((address_space(3))) unsigned int*)l, 16, 0, 0);
}

#define MASK_NONE 0x7fffffffu

// ---------------------------------------------------------------------------
// BK=64 dual-slab GEMM core (k_vt path / k_fbig): one barrier pair per 64 K.
// ---------------------------------------------------------------------------
template<int BM, int BN, int WMW, int WNW>
__device__ __forceinline__ void gemm_core64(
    const u16* __restrict__ A, int lda,
    const u16* __restrict__ Bm, int ldb,
    int K, int trow, int tcol,
    u16* As, u16* Bs,
    f32x4 (&acc)[BM / WMW / 16][BN / WNW / 16])
{
    constexpr int FM = BM / WMW / 16;
    constexpr int FN = BN / WNW / 16;
    const int tid  = threadIdx.x;
    const int wid  = tid >> 6, lane = tid & 63;
    const int wm   = wid % WMW, wn = wid / WMW;
    const int wr   = wm * (BM / WMW), wc = wn * (BN / WNW);
    const int lrow = lane & 15, lk = (lane >> 4) * 8;

    for (int kt = 0; kt < K; kt += 64) {
        __syncthreads();
#pragma unroll
        for (int s = 0; s < 2; s++) {
#pragma unroll
            for (int i = 0; i < BM / 64; i++) {       // stage A slab s
                int c = i * 256 + tid;
                int row = c >> 2, kg = c & 3;
                gload16(A + (size_t)(trow + row) * lda + kt + s * 32 + kg * 8,
                        As + (size_t)s * BM * 32 + (size_t)c * 8);
            }
#pragma unroll
            for (int i = 0; i < BN / 64; i++) {       // stage B slab s
                int c = i * 256 + tid;
                int col = c >> 2, kg = c & 3;
                gload16(Bm + (size_t)(tcol + col) * ldb + kt + s * 32 + kg * 8,
                        Bs + (size_t)s * BN * 32 + (size_t)c * 8);
            }
        }
        __syncthreads();

#pragma unroll
        for (int s = 0; s < 2; s++) {
            bf16x8 af[FM], bfr[FN];
#pragma unroll
            for (int fm = 0; fm < FM; fm++)
                af[fm] = *(const bf16x8*)&As[s * BM * 32 + (wr + fm * 16 + lrow) * 32 + lk];
#pragma unroll
            for (int fn = 0; fn < FN; fn++)
                bfr[fn] = *(const bf16x8*)&Bs[s * BN * 32 + (wc + fn * 16 + lrow) * 32 + lk];
#pragma unroll
            for (int fm = 0; fm < FM; fm++)
#pragma unroll
                for (int fn = 0; fn < FN; fn++)
                    acc[fm][fn] = __builtin_amdgcn_mfma_f32_16x16x32_bf16(
                        af[fm], bfr[fn], acc[fm][fn], 0, 0, 0);
        }
    }
}

// ---------------------------------------------------------------------------
// prep_all: merged independent input preps (block-range dispatch).
// ---------------------------------------------------------------------------
__global__ void prep_all(const float* x, const float* Wk, const float* Wcq,
                         const float* Wv, const float* Wx,
                         const float* bk, const float* bcq, const float* bv,
                         const float* bx,
                         const float* ctx, const float* Wck, const float* bck,
                         const float* Wcv, const float* bcv, const float* smix,
                         u16* xs, float* CKF, float* CQF, u16* wV,
                         float* biasKQ, float* biasV, float* kcf, u16* vcT)
{
    int blk = blockIdx.x;
    if (blk < 16384) {                       // ---- prep_x ----
        int t = blk * 256 + threadIdx.x;     // 2*16384*512/4
        int n = t >> 7, e4 = (t & 127) << 2;
        f32x4 v = *(const f32x4*)(x + (size_t)n * 512 + e4);
        u16x4 hi;
#pragma unroll
        for (int j = 0; j < 4; j++) hi[j] = f2bf(v[j]);
        *(u16x4*)(xs + (size_t)n * 512 + e4) = hi;
    } else if (blk < 19456) {                // ---- prep_w ----
        int idx = (blk - 16384) * 256 + threadIdx.x;  // 3*512*512
        int which = idx >> 18;
        int rem = idx & 262143;
        int c = rem >> 9, e = rem & 511;
        int h = c >> 6, d = c & 63;
        const float* W = which == 0 ? Wk : (which == 1 ? Wcq : Wv);
        float s = 0.f;
#pragma unroll 8
        for (int j = 0; j < 64; j++)
            s += W[d * 64 + j] * Wx[(h * 64 + j) * 512 + e];
        if (which == 0)      CKF[(size_t)c * 512 + e] = s;
        else if (which == 1) CQF[(size_t)c * 512 + e] = s;
        else                 wV [(size_t)c * 512 + e] = f2bf(s);
    } else if (blk < 19712) {                // ---- prep_ctx ----
        int t = (blk - 19456) * 256 + threadIdx.x;    // 16*64*64
        int bh = t >> 12, r = t & 4095;
        int s_ = r >> 6, d = r & 63;
        const float* crow = ctx + ((size_t)bh * 64 + s_) * 64;
        float kc = bck[d], vc = bcv[d];
#pragma unroll 8
        for (int e = 0; e < 64; e++) {
            float ce = crow[e];
            kc += ce * Wck[d * 64 + e];
            vc += ce * Wcv[d * 64 + e];
        }
        kcf[(size_t)bh * 4096 + s_ * 64 + d] = kc;
        float w = 1.f / (1.f + __expf(-smix[0]));
        int pos = (s_ & 15) * 4 + (s_ >> 4);
        vcT[(size_t)bh * 4096 + pos * 64 + d] = f2bf((1.f - w) * vc);
    } else {                                 // ---- prep_bias ----
        int t = (blk - 19712) * 256 + threadIdx.x;    // 1536
        if (t < 1024) {
            const float* W  = (t < 512) ? Wk : Wcq;
            const float* bb = (t < 512) ? bk : bcq;
            int c = t & 511; int h = c >> 6, d = c & 63;
            float s = bb[d];
            for (int j = 0; j < 64; j++) s += W[d * 64 + j] * bx[h * 64 + j];
            biasKQ[t] = s;
        } else if (t < 1536) {
            int c = t - 1024; int h = c >> 6, d = c & 63;
            float s = bv[d];
            for (int j = 0; j < 64; j++) s += Wv[d * 64 + j] * bx[h * 64 + j];
            biasV[c] = s;
        }
    }
}

// Merged: kg rows (BigB 0..511 [lo|hi], both b), kq rows (512+hs), CC consts.
__global__ void prep_b2(const float* CKF, const float* CQF, const float* qg,
                        const float* kcf, const float* biasKQ, u16* BigB, float* CC)
{
    int idx = blockIdx.x * 256 + threadIdx.x;     // 262144 + 524288 + 1536
    if (idx < 262144) {
        int hm = idx >> 9, e = idx & 511;
        int h = hm >> 6;
        float s = 0.f;
#pragma unroll 8
        for (int d = 0; d < 64; d++)
            s += CKF[(size_t)(h * 64 + d) * 512 + e] * qg[(size_t)hm * 64 + d];
        u16 hi = f2bf(s), lo = f2bf(s - bf2f(hi));
#pragma unroll
        for (int b = 0; b < 2; b++) {
            size_t base = (size_t)b * 1048576 + (size_t)hm * 1024;
            BigB[base + e]       = lo;
            BigB[base + 512 + e] = hi;
        }
    } else if (idx < 786432) {
        int i2 = idx - 262144;
        int r = i2 >> 9, e = i2 & 511;
        int b = r >> 9, hs = r & 511;
        int h = hs >> 6, s_ = hs & 63;
        float s = 0.f;
#pragma unroll 8
        for (int d = 0; d < 64; d++)
            s += CQF[(size_t)(h * 64 + d) * 512 + e]
               * kcf[(size_t)(b * 8 + h) * 4096 + s_ * 64 + d];
        u16 hi = f2bf(s), lo = f2bf(s - bf2f(hi));
        size_t base = (size_t)b * 1048576 + (size_t)(512 + hs) * 1024;
        BigB[base + e]       = lo;
        BigB[base + 512 + e] = hi;
    } else if (idx < 787968) {
        int t = idx - 786432;                     // 0..1535
        if (t < 512) {
            int h = t >> 6;
            float s = 0.f;
            for (int d = 0; d < 64; d++) s += biasKQ[h * 64 + d] * qg[(size_t)t * 64 + d];
            CC[t] = s; CC[1024 + t] = s;
        } else {
            int j = t - 512;
            int b = j >> 9, hs = j & 511;
            int h = hs >> 6, s_ = hs & 63;
            float s = 0.f;
            for (int d = 0; d < 64; d++)
                s += biasKQ[512 + h * 64 + d]
                   * kcf[(size_t)(b * 8 + h) * 4096 + s_ * 64 + d];
            CC[b * 1024 + 512 + hs] = s;
        }
    }
}

// ---------------------------------------------------------------------------
// k_Lvt: merged logits + V-transpose kernel (block-range dispatch).
//   blocks [0,2048):    k_L path  - 128n x 128cols logit tile, K=1024,
//                       R13 A-reuse form (24KB of the LDS union).
//   blocks [2048,3072): k_vt path - vT = CV @ xs^T tile (BK=64, 32KB LDS).
// Both paths byte-identical math to R15/R16; k_vt blocks fill k_L's tail.
// ---------------------------------------------------------------------------
__global__ void k_Lvt(const u16* xs, const u16* BigB, const float* CC,
                      const u16* wV, const float* biasV,
                      u16* P12, float* DD, u16* vT)
{
    __shared__ u16 sh[16384];            // 32KB union
    int f0 = blockIdx.x;
    int tid = threadIdx.x, wid = tid >> 6, lane = tid & 63;
    int lrow = lane & 15, lk = (lane >> 4) * 8;

    if (f0 < 2048) {
        // ------------------------- k_L path -------------------------
        u16* As   = sh;                  // 128*32
        u16* BsLo = sh + 4096;           // 128*32
        u16* BsHi = sh + 8192;           // 128*32
        f32x4 acc[4][4] = {};
        int w = (f0 & 7) * 256 + (f0 >> 3);   // XCD-chunked, bijective
        int jt = w & 7, nb = w >> 3;
        int b = nb >> 7, ntile = nb & 127;
        int trow = ntile * 128, tcol = jt * 128;
        const u16* A  = xs   + (size_t)b * 8388608;
        const u16* Bm = BigB + (size_t)b * 1048576;
        int wm = wid & 1, wn = wid >> 1;
        int wr = wm * 64, wc = wn * 64;

        for (int kt = 0; kt < 512; kt += 32) {
            __syncthreads();
#pragma unroll
            for (int i = 0; i < 2; i++) {             // stage A once
                int c = i * 256 + tid;
                int row = c >> 2, kg = c & 3;
                gload16(A + (size_t)(trow + row) * 512 + kt + kg * 8,
                        As + (size_t)c * 8);
            }
#pragma unroll
            for (int i = 0; i < 2; i++) {             // stage B lo + hi
                int c = i * 256 + tid;
                int col = c >> 2, kg = c & 3;
                gload16(Bm + (size_t)(tcol + col) * 1024 + kt + kg * 8,
                        BsLo + (size_t)c * 8);
                gload16(Bm + (size_t)(tcol + col) * 1024 + 512 + kt + kg * 8,
                        BsHi + (size_t)c * 8);
            }
            __syncthreads();

            bf16x8 af[4], bfr[4];
#pragma unroll
            for (int fm = 0; fm < 4; fm++)
                af[fm] = *(const bf16x8*)&As[(wr + fm * 16 + lrow) * 32 + lk];
#pragma unroll
            for (int fn = 0; fn < 4; fn++)
                bfr[fn] = *(const bf16x8*)&BsLo[(wc + fn * 16 + lrow) * 32 + lk];
#pragma unroll
            for (int fm = 0; fm < 4; fm++)
#pragma unroll
                for (int fn = 0; fn < 4; fn++)
                    acc[fm][fn] = __builtin_amdgcn_mfma_f32_16x16x32_bf16(
                        af[fm], bfr[fn], acc[fm][fn], 0, 0, 0);
#pragma unroll
            for (int fn = 0; fn < 4; fn++)
                bfr[fn] = *(const bf16x8*)&BsHi[(wc + fn * 16 + lrow) * 32 + lk];
#pragma unroll
            for (int fm = 0; fm < 4; fm++)
#pragma unroll
                for (int fn = 0; fn < 4; fn++)
                    acc[fm][fn] = __builtin_amdgcn_mfma_f32_16x16x32_bf16(
                        af[fm], bfr[fn], acc[fm][fn], 0, 0, 0);
        }

        int g = lane >> 4, li = lane & 15;
        float cj[4];
#pragma unroll
        for (int fn = 0; fn < 4; fn++)
            cj[fn] = CC[b * 1024 + tcol + wc + fn * 16 + li];

        int h = jt * 2 + wn;             // head index within dec half (jt<4)
#pragma unroll
        for (int fm = 0; fm < 4; fm++)
#pragma unroll
            for (int j = 0; j < 4; j++) {
                float ev[4]; float dsum = 0.f;
#pragma unroll
                for (int fn = 0; fn < 4; fn++) {
                    ev[fn] = __expf(acc[fm][fn][j] + cj[fn]);
                    dsum += ev[fn];
                }
                dsum += __shfl_xor(dsum, 1); dsum += __shfl_xor(dsum, 2);
                dsum += __shfl_xor(dsum, 4); dsum += __shfl_xor(dsum, 8);
                float inv = 1.f / dsum;
                int row = trow + wr + fm * 16 + g * 4 + j;
                size_t pb = ((size_t)b * 16384 + row) * 1024 + tcol + wc;
                u16x4 pk;
#pragma unroll
                for (int fn = 0; fn < 4; fn++) pk[fn] = f2bf(ev[fn] * inv);
                *(u16x4*)(P12 + pb + li * 4) = pk;
                if (jt < 4 && li == 0)
                    DD[(size_t)(b * 8 + h) * 16384 + row] = dsum;
            }
    } else {
        // ------------------------- k_vt path -------------------------
        u16* As = sh;                    // 128*64
        u16* Bs = sh + 8192;             // 128*64
        f32x4 acc[4][4] = {};
        int idx = f0 - 2048;             // [0,1024)
        int b = idx >> 9;
        int f = idx & 511;
        int w = (f & 7) * 64 + (f >> 3);
        int trow = (w & 3) * 128;
        int tcol = (w >> 2) * 128;
        gemm_core64<128, 128, 2, 2>(wV, 512, xs + (size_t)b * 8388608, 512,
                                    512, trow, tcol, As, Bs, acc);
        int wr = (wid & 1) * 64, wc = (wid >> 1) * 64;
        int g = lane >> 4, li = lane & 15;
#pragma unroll
        for (int fm = 0; fm < 4; fm++)
#pragma unroll
            for (int fn = 0; fn < 4; fn++) {
                int col = tcol + wc + fn * 16 + li;
#pragma unroll
                for (int j = 0; j < 4; j++) {
                    int a = trow + wr + fm * 16 + g * 4 + j;
                    vT[((size_t)b * 512 + a) * 16384 + col]
                        = f2bf(acc[fm][fn][j] + biasV[a]);
                }
            }
    }
}

// ---------------------------------------------------------------------------
// latT (+ fused dene): latp[ch][bh][d][m] = sum_n vT[d][n]*(P12dec[n][h,m]*DD[n])
// (split-K 32).  Staging values v = P*DD (f32) also accumulated into dacc[8]
// and reduced to denp[(bh*64+m)][ch] at the end.
// ---------------------------------------------------------------------------
__global__ __launch_bounds__(256, 2) void k_latT(const u16* vT, const u16* P12,
                                                 const float* DD, float* latp,
                                                 float* denp)
{
    __shared__ u16 sh2[4096];            // As[2048] | Bs[2048]; reduce as f32[2048]
    u16* As = sh2;
    u16* Bs = sh2 + 2048;
    f32x4 acc[2][2] = {};
    float dacc[8] = {0.f, 0.f, 0.f, 0.f, 0.f, 0.f, 0.f, 0.f};
    int ch = blockIdx.x, bh = blockIdx.z;
    int b = bh >> 3, h = bh & 7;
    int koff = ch * 512;
    int tid = threadIdx.x, wid = tid >> 6, lane = tid & 63;
    int wr = (wid & 1) * 32, wc = (wid >> 1) * 32;
    int lrow = lane & 15, lk = (lane >> 4) * 8;
    const u16* Avt = vT + (size_t)bh * 64 * 16384;
    int nl = tid & 31, m0 = (tid >> 5) * 8;

    for (int kt = 0; kt < 512; kt += 32) {
        __syncthreads();
        {   // stage A: vT rows 64 x 32k
            int row = tid >> 2, kg = tid & 3;
            gload16(Avt + (size_t)row * 16384 + koff + kt + kg * 8, As + (size_t)tid * 8);
        }
        {   // stage B transposed: Bs[m][n], XOR-swizzled; accumulate dene
            int n = koff + kt + nl;
            const u16* src = P12 + ((size_t)b * 16384 + n) * 1024 + h * 64 + m0;
            u16x4 p0 = *(const u16x4*)src;
            u16x4 p1 = *(const u16x4*)(src + 4);
            float ddv = DD[(size_t)bh * 16384 + n];
#pragma unroll
            for (int i = 0; i < 4; i++) {
                int m = m0 + i;
                float v = bf2f(p0[i]) * ddv;
                dacc[i] += v;
                Bs[m * 32 + (nl ^ ((m & 3) << 3))] = f2bf(v);
            }
#pragma unroll
            for (int i = 0; i < 4; i++) {
                int m = m0 + 4 + i;
                float v = bf2f(p1[i]) * ddv;
                dacc[4 + i] += v;
                Bs[m * 32 + (nl ^ ((m & 3) << 3))] = f2bf(v);
            }
        }
        __syncthreads();
        bf16x8 af[2], bfv[2];
#pragma unroll
        for (int fm = 0; fm < 2; fm++)
            af[fm] = *(const bf16x8*)&As[(wr + fm * 16 + lrow) * 32 + lk];
#pragma unroll
        for (int fn = 0; fn < 2; fn++) {
            int m = wc + fn * 16 + lrow;
            bfv[fn] = *(const bf16x8*)&Bs[m * 32 + (lk ^ ((m & 3) << 3))];
        }
#pragma unroll
        for (int fm = 0; fm < 2; fm++)
#pragma unroll
            for (int fn = 0; fn < 2; fn++)
                acc[fm][fn] = __builtin_amdgcn_mfma_f32_16x16x32_bf16(
                    af[fm], bfv[fn], acc[fm][fn], 0, 0, 0);
    }
    float* C = latp + ((size_t)ch * 16 + bh) * 4096;
    int g = lane >> 4, li = lane & 15;
#pragma unroll
    for (int fm = 0; fm < 2; fm++)
#pragma unroll
        for (int fn = 0; fn < 2; fn++)
#pragma unroll
            for (int j = 0; j < 4; j++) {
                int row = wr + fm * 16 + g * 4 + j;   // d
                int col = wc + fn * 16 + li;          // m
                C[row * 64 + col] = acc[fm][fn][j];
            }
    // dene reduce: red[m][nl] = dacc; 64 rows sum 32 partials -> denp.
    __syncthreads();                     // all waves done reading As/Bs
    float* red = (float*)sh2;            // 2048 f32 = 8KB
#pragma unroll
    for (int i = 0; i < 8; i++)
        red[(m0 + i) * 32 + nl] = dacc[i];
    __syncthreads();
    if (tid < 64) {
        float s = 0.f;
        const float* rr = red + tid * 32;
        for (int j = 0; j < 32; j++) s += rr[j];
        denp[(size_t)(bh * 64 + tid) * 32 + ch] = s;
    }
}

// finish latent (+ inline den reduce): latB[bh][m][d] =
//   w * (sum_ch latp[d][m]) / (sum_c denp)    ([pos][d] layout for prep_g)
__global__ void k_latfin(const float* latp, const float* denp, const float* smix,
                         u16* latB)
{
    int t = blockIdx.x * 256 + threadIdx.x;       // 16*64*64
    int bh = t >> 12, r = t & 4095;
    int d = r >> 6, m = r & 63;
    float w = 1.f / (1.f + __expf(-smix[0]));
    float s = 0.f;
    for (int c = 0; c < 32; c++) s += latp[((size_t)c * 16 + bh) * 4096 + r];
    float dd = 0.f;
    const float* dp = denp + (size_t)(bh * 64 + m) * 32;
    for (int c = 0; c < 32; c++) dd += dp[c];
    latB[(size_t)bh * 4096 + m * 64 + d] = f2bf(w * s / dd);
}

// ---------------------------------------------------------------------------
// prep_g: G[b][e][k] = sum_d (k<512 ? latB : vcT)[b,h(k)][k&63][d] * Wo[e][h*64+d]
// ---------------------------------------------------------------------------
__global__ void prep_g(const u16* latB, const u16* vcT, const float* Wo, u16* G)
{
    int idx = blockIdx.x * 256 + threadIdx.x;     // 2*512*1024
    int b = idx >> 19;
    int r = idx & 524287;
    int e = r >> 10, k = r & 1023;
    int h = (k >> 6) & 7, dm = k & 63;
    const u16* src = (k < 512) ? latB : vcT;
    const float* wrow = Wo + (size_t)e * 512 + h * 64;
    const u16* sb = src + (size_t)(b * 8 + h) * 4096 + dm * 64;
    float s = 0.f;
#pragma unroll
    for (int d0 = 0; d0 < 64; d0 += 4) {
        u16x4 sv = *(const u16x4*)(sb + d0);
        f32x4 wv = *(const f32x4*)(wrow + d0);
        s += bf2f(sv[0]) * wv[0] + bf2f(sv[1]) * wv[1]
           + bf2f(sv[2]) * wv[2] + bf2f(sv[3]) * wv[3];
    }
    G[(size_t)b * 524288 + (size_t)e * 1024 + k] = f2bf(s);
}

// ---------------------------------------------------------------------------
// k_fbig: out(fp32) = P12 @ G[b]^T + bo   (K=1024, BK=64 core)
// ---------------------------------------------------------------------------
__global__ __launch_bounds__(256, 2) void k_fbig(const u16* P12, const u16* G,
                                                 const float* bo, float* out)
{
    __shared__ u16 As[128 * 64], Bs[128 * 64];
    f32x4 acc[4][4] = {};
    int f = blockIdx.y * gridDim.x + blockIdx.x;       // 1024 blocks
    int w = (f & 7) * 128 + (f >> 3);
    int tcol = (w & 3) * 128, trow = (w >> 2) * 128;
    int b = trow >> 14;
    gemm_core64<128, 128, 2, 2>(P12, 1024, G + (size_t)b * 524288, 1024,
                                1024, trow, tcol, As, Bs, acc);
    int tid = threadIdx.x, wid = tid >> 6, lane = tid & 63;
    int wr = (wid & 1) * 64, wc = (wid >> 1) * 64;
    int g = lane >> 4, li = lane & 15;
#pragma unroll
    for (int fm = 0; fm < 4; fm++)
#pragma unroll
        for (int fn = 0; fn < 4; fn++) {
            int col = tcol + wc + fn * 16 + li;
            float bias = bo[col];
#pragma unroll
            for (int j = 0; j < 4; j++) {
                int row = trow + wr + fm * 16 + g * 4 + j;
                out[(size_t)row * 512 + col] = acc[fm][fn][j] + bias;
            }
        }
}

// ---------------------------------------------------------------------------
// Workspace layout (bytes), end ~154 MB (< proven-safe 209.7 MB). No aliases.
// ---------------------------------------------------------------------------
static const size_t XS_OFF   = 0;            // u16 32768x512    (33,554,432)
static const size_t P12_OFF  = 33554432;     // u16 2x16384x1024 (67,108,864)
static const size_t VT_OFF   = 100663296;    // u16 2x512x16384  (33,554,432)
static const size_t CKF_OFF  = 134217728;    // f32 512x512      (1,048,576)
static const size_t CQF_OFF  = 135266304;    // f32 512x512      (1,048,576)
static const size_t WV_OFF   = 136314880;    // u16 512x512      (524,288)
static const size_t BIGB_OFF = 136839168;    // u16 2x1024x1024  (4,194,304)
static const size_t KCF_OFF  = 141033472;    // f32 16x64x64     (262,144)
static const size_t VCT_OFF  = 141295616;    // u16 16x64x64     (131,072)
static const size_t BKQ_OFF  = 141426688;    // f32 1024         (4,096)
static const size_t BV_OFF   = 141430784;    // f32 512          (2,048)
static const size_t CC_OFF   = 141432832;    // f32 2048         (8,192)
static const size_t DENP_OFF = 141441024;    // f32 1024x32      (131,072)
static const size_t DD_OFF   = 141965312;    // f32 16x16384     (1,048,576)
static const size_t LATP_OFF = 143013888;    // f32 32x16x64x64  (8,388,608)
static const size_t LATB_OFF = 151402496;    // u16 16x64x64     (131,072)
static const size_t G_OFF    = 151533568;    // u16 2x512x1024   (2,097,152)
// end: 153,630,720

extern "C" void kernel_launch(void* const* d_in, const int* in_sizes, int n_in,
                              void* d_out, int out_size, void* d_ws, size_t ws_size,
                              hipStream_t stream)
{
    const float* x    = (const float*)d_in[0];
    const float* ctx  = (const float*)d_in[1];
    const float* qg   = (const float*)d_in[2];
    const float* Wx   = (const float*)d_in[3];
    const float* bx   = (const float*)d_in[4];
    const float* Wk   = (const float*)d_in[5];
    const float* bk   = (const float*)d_in[6];
    const float* Wv   = (const float*)d_in[7];
    const float* bv   = (const float*)d_in[8];
    const float* Wcq  = (const float*)d_in[9];
    const float* bcq  = (const float*)d_in[10];
    const float* Wck  = (const float*)d_in[11];
    const float* bck  = (const float*)d_in[12];
    const float* Wcv  = (const float*)d_in[13];
    const float* bcv  = (const float*)d_in[14];
    const float* smix = (const float*)d_in[15];
    const float* Wo   = (const float*)d_in[16];
    const float* bo   = (const float*)d_in[17];

    char* ws = (char*)d_ws;
    u16*   xs    = (u16*)  (ws + XS_OFF);
    u16*   P12   = (u16*)  (ws + P12_OFF);
    u16*   vT    = (u16*)  (ws + VT_OFF);
    float* CKF   = (float*)(ws + CKF_OFF);
    float* CQF   = (float*)(ws + CQF_OFF);
    u16*   wV    = (u16*)  (ws + WV_OFF);
    u16*   BigB  = (u16*)  (ws + BIGB_OFF);
    float* kcf   = (float*)(ws + KCF_OFF);
    u16*   vcT   = (u16*)  (ws + VCT_OFF);
    float* biasKQ= (float*)(ws + BKQ_OFF);
    float* biasV = (float*)(ws + BV_OFF);
    float* CC    = (float*)(ws + CC_OFF);
    float* denp  = (float*)(ws + DENP_OFF);
    float* DD    = (float*)(ws + DD_OFF);
    float* latp  = (float*)(ws + LATP_OFF);
    u16*   latB  = (u16*)  (ws + LATB_OFF);
    u16*   G     = (u16*)  (ws + G_OFF);

    prep_all<<<19718, 256, 0, stream>>>(x, Wk, Wcq, Wv, Wx, bk, bcq, bv, bx,
                                        ctx, Wck, bck, Wcv, bcv, smix,
                                        xs, CKF, CQF, wV, biasKQ, biasV, kcf, vcT);
    prep_b2 <<< 3078, 256, 0, stream>>>(CKF, CQF, qg, kcf, biasKQ, BigB, CC);

    k_Lvt   <<<3072, 256, 0, stream>>>(xs, BigB, CC, wV, biasV, P12, DD, vT);
    k_latT  <<<dim3( 32,   1, 16), 256, 0, stream>>>(vT, P12, DD, latp, denp);
    k_latfin<<< 256, 256, 0, stream>>>(latp, denp, smix, latB);
    prep_g  <<<4096, 256, 0, stream>>>(latB, vcT, Wo, G);
    k_fbig  <<<dim3(  4, 256, 1), 256, 0, stream>>>(P12, G, bo, (float*)d_out);
}

// Round 19
// 238.557 us; speedup vs baseline: 1.1151x; 1.0202x over previous
//
#include <hip/hip_runtime.h>

// ---------------------------------------------------------------------------
// GALE_FA: FLARE low-rank self-attn + context cross-attn + gated mix.
// R4: logits computed directly from x (k/q never materialized).
// R8: K-cut 1536->1024 (drop xl*Bhi), xs hi-only.
// R9/R10: slim unified k_L; OM folded through Wo (G), k_fbig K=1024.
// R11: position-permuted P12 columns.  R13: k_L A-reuse (32 MFMA/barrier).
// R14: BK=64 dual-slab for k_vt/k_fbig.  R16: dene fused into k_latT.
// R17: k_vt merged into k_L (block-range dispatch).
// R18: prep chain reshaped - prep_small (weights/ctx/bias) then prep_big
// (x-conv || BigB/CC || G-cross, all independent); only G-dec (prep_gd)
// remains on the latent critical path. 7 launches, shorter chain.
// ---------------------------------------------------------------------------

typedef unsigned short u16;
typedef __attribute__((ext_vector_type(4))) float  f32x4;
typedef __attribute__((ext_vector_type(4))) u16    u16x4;
typedef __attribute__((ext_vector_type(8))) __bf16 bf16x8;

__device__ __forceinline__ float bf2f(u16 u) {
    return __uint_as_float(((unsigned)u) << 16);
}
__device__ __forceinline__ u16 f2bf(float f) {   // round-to-nearest-even
    unsigned u = __float_as_uint(f);
    u += 0x7fffu + ((u >> 16) & 1u);
    return (u16)(u >> 16);
}
__device__ __forceinline__ void gload16(const void* g, void* l) {
    __builtin_amdgcn_global_load_lds(
        (const __attribute__((address_space(1))) unsigned int*)g,
        (__attribute__((address_space(3))) unsigned int*)l, 16, 0, 0);
}

#define MASK_NONE 0x7fffffffu

// ---------------------------------------------------------------------------
// BK=64 dual-slab GEMM core (k_vt path / k_fbig): one barrier pair per 64 K.
// ---------------------------------------------------------------------------
template<int BM, int BN, int WMW, int WNW>
__device__ __forceinline__ void gemm_core64(
    const u16* __restrict__ A, int lda,
    const u16* __restrict__ Bm, int ldb,
    int K, int trow, int tcol,
    u16* As, u16* Bs,
    f32x4 (&acc)[BM / WMW / 16][BN / WNW / 16])
{
    constexpr int FM = BM / WMW / 16;
    constexpr int FN = BN / WNW / 16;
    const int tid  = threadIdx.x;
    const int wid  = tid >> 6, lane = tid & 63;
    const int wm   = wid % WMW, wn = wid / WMW;
    const int wr   = wm * (BM / WMW), wc = wn * (BN / WNW);
    const int lrow = lane & 15, lk = (lane >> 4) * 8;

    for (int kt = 0; kt < K; kt += 64) {
        __syncthreads();
#pragma unroll
        for (int s = 0; s < 2; s++) {
#pragma unroll
            for (int i = 0; i < BM / 64; i++) {       // stage A slab s
                int c = i * 256 + tid;
                int row = c >> 2, kg = c & 3;
                gload16(A + (size_t)(trow + row) * lda + kt + s * 32 + kg * 8,
                        As + (size_t)s * BM * 32 + (size_t)c * 8);
            }
#pragma unroll
            for (int i = 0; i < BN / 64; i++) {       // stage B slab s
                int c = i * 256 + tid;
                int col = c >> 2, kg = c & 3;
                gload16(Bm + (size_t)(tcol + col) * ldb + kt + s * 32 + kg * 8,
                        Bs + (size_t)s * BN * 32 + (size_t)c * 8);
            }
        }
        __syncthreads();

#pragma unroll
        for (int s = 0; s < 2; s++) {
            bf16x8 af[FM], bfr[FN];
#pragma unroll
            for (int fm = 0; fm < FM; fm++)
                af[fm] = *(const bf16x8*)&As[s * BM * 32 + (wr + fm * 16 + lrow) * 32 + lk];
#pragma unroll
            for (int fn = 0; fn < FN; fn++)
                bfr[fn] = *(const bf16x8*)&Bs[s * BN * 32 + (wc + fn * 16 + lrow) * 32 + lk];
#pragma unroll
            for (int fm = 0; fm < FM; fm++)
#pragma unroll
                for (int fn = 0; fn < FN; fn++)
                    acc[fm][fn] = __builtin_amdgcn_mfma_f32_16x16x32_bf16(
                        af[fm], bfr[fn], acc[fm][fn], 0, 0, 0);
        }
    }
}

// ---------------------------------------------------------------------------
// prep_small: composed weights, context, biases (everything prep_big needs).
//   blocks [0,3072)      prep_w : CKF/CQF fp32, wV bf16
//   blocks [3072,3328)   prep_ctx: kc fp32; vcT bf16 [bh][pos(s)][d]
//   blocks [3328,3334)   prep_bias: biasKQ / biasV
// ---------------------------------------------------------------------------
__global__ void prep_small(const float* Wk, const float* Wcq, const float* Wv,
                           const float* Wx,
                           const float* bk, const float* bcq, const float* bv,
                           const float* bx,
                           const float* ctx, const float* Wck, const float* bck,
                           const float* Wcv, const float* bcv, const float* smix,
                           float* CKF, float* CQF, u16* wV,
                           float* biasKQ, float* biasV, float* kcf, u16* vcT)
{
    int blk = blockIdx.x;
    if (blk < 3072) {                        // ---- prep_w ----
        int idx = blk * 256 + threadIdx.x;   // 3*512*512
        int which = idx >> 18;
        int rem = idx & 262143;
        int c = rem >> 9, e = rem & 511;
        int h = c >> 6, d = c & 63;
        const float* W = which == 0 ? Wk : (which == 1 ? Wcq : Wv);
        float s = 0.f;
#pragma unroll 8
        for (int j = 0; j < 64; j++)
            s += W[d * 64 + j] * Wx[(h * 64 + j) * 512 + e];
        if (which == 0)      CKF[(size_t)c * 512 + e] = s;
        else if (which == 1) CQF[(size_t)c * 512 + e] = s;
        else                 wV [(size_t)c * 512 + e] = f2bf(s);
    } else if (blk < 3328) {                 // ---- prep_ctx ----
        int t = (blk - 3072) * 256 + threadIdx.x;     // 16*64*64
        int bh = t >> 12, r = t & 4095;
        int s_ = r >> 6, d = r & 63;
        const float* crow = ctx + ((size_t)bh * 64 + s_) * 64;
        float kc = bck[d], vc = bcv[d];
#pragma unroll 8
        for (int e = 0; e < 64; e++) {
            float ce = crow[e];
            kc += ce * Wck[d * 64 + e];
            vc += ce * Wcv[d * 64 + e];
        }
        kcf[(size_t)bh * 4096 + s_ * 64 + d] = kc;
        float w = 1.f / (1.f + __expf(-smix[0]));
        int pos = (s_ & 15) * 4 + (s_ >> 4);
        vcT[(size_t)bh * 4096 + pos * 64 + d] = f2bf((1.f - w) * vc);
    } else {                                 // ---- prep_bias ----
        int t = (blk - 3328) * 256 + threadIdx.x;     // 1536
        if (t < 1024) {
            const float* W  = (t < 512) ? Wk : Wcq;
            const float* bb = (t < 512) ? bk : bcq;
            int c = t & 511; int h = c >> 6, d = c & 63;
            float s = bb[d];
            for (int j = 0; j < 64; j++) s += W[d * 64 + j] * bx[h * 64 + j];
            biasKQ[t] = s;
        } else if (t < 1536) {
            int c = t - 1024; int h = c >> 6, d = c & 63;
            float s = bv[d];
            for (int j = 0; j < 64; j++) s += Wv[d * 64 + j] * bx[h * 64 + j];
            biasV[c] = s;
        }
    }
}

// ---------------------------------------------------------------------------
// prep_big: three independent jobs (given prep_small outputs):
//   blocks [0,16384)       prep_x : x -> xs bf16 hi (HBM-bound stream)
//   blocks [16384,19462)   prep_b2: BigB [lo|hi] rows + CC consts
//   blocks [19462,21510)   prep_gc: G cross half (k>=512) from vcT x Wo
// ---------------------------------------------------------------------------
__global__ void prep_big(const float* x, const float* CKF, const float* CQF,
                         const float* qg, const float* kcf, const float* biasKQ,
                         const u16* vcT, const float* Wo,
                         u16* xs, u16* BigB, float* CC, u16* G)
{
    int blk = blockIdx.x;
    if (blk < 16384) {                       // ---- prep_x ----
        int t = blk * 256 + threadIdx.x;     // 2*16384*512/4
        int n = t >> 7, e4 = (t & 127) << 2;
        f32x4 v = *(const f32x4*)(x + (size_t)n * 512 + e4);
        u16x4 hi;
#pragma unroll
        for (int j = 0; j < 4; j++) hi[j] = f2bf(v[j]);
        *(u16x4*)(xs + (size_t)n * 512 + e4) = hi;
    } else if (blk < 19462) {                // ---- prep_b2 ----
        int idx = (blk - 16384) * 256 + threadIdx.x;  // 262144+524288+1536
        if (idx < 262144) {
            int hm = idx >> 9, e = idx & 511;
            int h = hm >> 6;
            float s = 0.f;
#pragma unroll 8
            for (int d = 0; d < 64; d++)
                s += CKF[(size_t)(h * 64 + d) * 512 + e] * qg[(size_t)hm * 64 + d];
            u16 hi = f2bf(s), lo = f2bf(s - bf2f(hi));
#pragma unroll
            for (int b = 0; b < 2; b++) {
                size_t base = (size_t)b * 1048576 + (size_t)hm * 1024;
                BigB[base + e]       = lo;
                BigB[base + 512 + e] = hi;
            }
        } else if (idx < 786432) {
            int i2 = idx - 262144;
            int r = i2 >> 9, e = i2 & 511;
            int b = r >> 9, hs = r & 511;
            int h = hs >> 6, s_ = hs & 63;
            float s = 0.f;
#pragma unroll 8
            for (int d = 0; d < 64; d++)
                s += CQF[(size_t)(h * 64 + d) * 512 + e]
                   * kcf[(size_t)(b * 8 + h) * 4096 + s_ * 64 + d];
            u16 hi = f2bf(s), lo = f2bf(s - bf2f(hi));
            size_t base = (size_t)b * 1048576 + (size_t)(512 + hs) * 1024;
            BigB[base + e]       = lo;
            BigB[base + 512 + e] = hi;
        } else if (idx < 787968) {
            int t = idx - 786432;                     // 0..1535
            if (t < 512) {
                int h = t >> 6;
                float s = 0.f;
                for (int d = 0; d < 64; d++)
                    s += biasKQ[h * 64 + d] * qg[(size_t)t * 64 + d];
                CC[t] = s; CC[1024 + t] = s;
            } else {
                int j = t - 512;
                int b = j >> 9, hs = j & 511;
                int h = hs >> 6, s_ = hs & 63;
                float s = 0.f;
                for (int d = 0; d < 64; d++)
                    s += biasKQ[512 + h * 64 + d]
                       * kcf[(size_t)(b * 8 + h) * 4096 + s_ * 64 + d];
                CC[b * 1024 + 512 + hs] = s;
            }
        }
    } else {                                 // ---- prep_gc (cross half) ----
        int idx2 = (blk - 19462) * 256 + threadIdx.x; // 2*512*512
        int b = idx2 >> 18;
        int rr = idx2 & 262143;
        int e = rr >> 9, kk = rr & 511;
        int k = 512 + kk;
        int h = kk >> 6, dm = kk & 63;
        const float* wrow = Wo + (size_t)e * 512 + h * 64;
        const u16* sb = vcT + (size_t)(b * 8 + h) * 4096 + dm * 64;
        float s = 0.f;
#pragma unroll
        for (int d0 = 0; d0 < 64; d0 += 4) {
            u16x4 sv = *(const u16x4*)(sb + d0);
            f32x4 wv = *(const f32x4*)(wrow + d0);
            s += bf2f(sv[0]) * wv[0] + bf2f(sv[1]) * wv[1]
               + bf2f(sv[2]) * wv[2] + bf2f(sv[3]) * wv[3];
        }
        G[(size_t)b * 524288 + (size_t)e * 1024 + k] = f2bf(s);
    }
}

// ---------------------------------------------------------------------------
// k_Lvt: merged logits + V-transpose kernel (block-range dispatch).
//   blocks [0,2048):    k_L path  - 128n x 128cols logit tile, K=1024,
//                       R13 A-reuse form (24KB of the LDS union).
//   blocks [2048,3072): k_vt path - vT = CV @ xs^T tile (BK=64, 32KB LDS).
// ---------------------------------------------------------------------------
__global__ void k_Lvt(const u16* xs, const u16* BigB, const float* CC,
                      const u16* wV, const float* biasV,
                      u16* P12, float* DD, u16* vT)
{
    __shared__ u16 sh[16384];            // 32KB union
    int f0 = blockIdx.x;
    int tid = threadIdx.x, wid = tid >> 6, lane = tid & 63;
    int lrow = lane & 15, lk = (lane >> 4) * 8;

    if (f0 < 2048) {
        // ------------------------- k_L path -------------------------
        u16* As   = sh;                  // 128*32
        u16* BsLo = sh + 4096;           // 128*32
        u16* BsHi = sh + 8192;           // 128*32
        f32x4 acc[4][4] = {};
        int w = (f0 & 7) * 256 + (f0 >> 3);   // XCD-chunked, bijective
        int jt = w & 7, nb = w >> 3;
        int b = nb >> 7, ntile = nb & 127;
        int trow = ntile * 128, tcol = jt * 128;
        const u16* A  = xs   + (size_t)b * 8388608;
        const u16* Bm = BigB + (size_t)b * 1048576;
        int wm = wid & 1, wn = wid >> 1;
        int wr = wm * 64, wc = wn * 64;

        for (int kt = 0; kt < 512; kt += 32) {
            __syncthreads();
#pragma unroll
            for (int i = 0; i < 2; i++) {             // stage A once
                int c = i * 256 + tid;
                int row = c >> 2, kg = c & 3;
                gload16(A + (size_t)(trow + row) * 512 + kt + kg * 8,
                        As + (size_t)c * 8);
            }
#pragma unroll
            for (int i = 0; i < 2; i++) {             // stage B lo + hi
                int c = i * 256 + tid;
                int col = c >> 2, kg = c & 3;
                gload16(Bm + (size_t)(tcol + col) * 1024 + kt + kg * 8,
                        BsLo + (size_t)c * 8);
                gload16(Bm + (size_t)(tcol + col) * 1024 + 512 + kt + kg * 8,
                        BsHi + (size_t)c * 8);
            }
            __syncthreads();

            bf16x8 af[4], bfr[4];
#pragma unroll
            for (int fm = 0; fm < 4; fm++)
                af[fm] = *(const bf16x8*)&As[(wr + fm * 16 + lrow) * 32 + lk];
#pragma unroll
            for (int fn = 0; fn < 4; fn++)
                bfr[fn] = *(const bf16x8*)&BsLo[(wc + fn * 16 + lrow) * 32 + lk];
#pragma unroll
            for (int fm = 0; fm < 4; fm++)
#pragma unroll
                for (int fn = 0; fn < 4; fn++)
                    acc[fm][fn] = __builtin_amdgcn_mfma_f32_16x16x32_bf16(
                        af[fm], bfr[fn], acc[fm][fn], 0, 0, 0);
#pragma unroll
            for (int fn = 0; fn < 4; fn++)
                bfr[fn] = *(const bf16x8*)&BsHi[(wc + fn * 16 + lrow) * 32 + lk];
#pragma unroll
            for (int fm = 0; fm < 4; fm++)
#pragma unroll
                for (int fn = 0; fn < 4; fn++)
                    acc[fm][fn] = __builtin_amdgcn_mfma_f32_16x16x32_bf16(
                        af[fm], bfr[fn], acc[fm][fn], 0, 0, 0);
        }

        int g = lane >> 4, li = lane & 15;
        float cj[4];
#pragma unroll
        for (int fn = 0; fn < 4; fn++)
            cj[fn] = CC[b * 1024 + tcol + wc + fn * 16 + li];

        int h = jt * 2 + wn;             // head index within dec half (jt<4)
#pragma unroll
        for (int fm = 0; fm < 4; fm++)
#pragma unroll
            for (int j = 0; j < 4; j++) {
                float ev[4]; float dsum = 0.f;
#pragma unroll
                for (int fn = 0; fn < 4; fn++) {
                    ev[fn] = __expf(acc[fm][fn][j] + cj[fn]);
                    dsum += ev[fn];
                }
                dsum += __shfl_xor(dsum, 1); dsum += __shfl_xor(dsum, 2);
                dsum += __shfl_xor(dsum, 4); dsum += __shfl_xor(dsum, 8);
                float inv = 1.f / dsum;
                int row = trow + wr + fm * 16 + g * 4 + j;
                size_t pb = ((size_t)b * 16384 + row) * 1024 + tcol + wc;
                u16x4 pk;
#pragma unroll
                for (int fn = 0; fn < 4; fn++) pk[fn] = f2bf(ev[fn] * inv);
                *(u16x4*)(P12 + pb + li * 4) = pk;
                if (jt < 4 && li == 0)
                    DD[(size_t)(b * 8 + h) * 16384 + row] = dsum;
            }
    } else {
        // ------------------------- k_vt path -------------------------
        u16* As = sh;                    // 128*64
        u16* Bs = sh + 8192;             // 128*64
        f32x4 acc[4][4] = {};
        int idx = f0 - 2048;             // [0,1024)
        int b = idx >> 9;
        int f = idx & 511;
        int w = (f & 7) * 64 + (f >> 3);
        int trow = (w & 3) * 128;
        int tcol = (w >> 2) * 128;
        gemm_core64<128, 128, 2, 2>(wV, 512, xs + (size_t)b * 8388608, 512,
                                    512, trow, tcol, As, Bs, acc);
        int wr = (wid & 1) * 64, wc = (wid >> 1) * 64;
        int g = lane >> 4, li = lane & 15;
#pragma unroll
        for (int fm = 0; fm < 4; fm++)
#pragma unroll
            for (int fn = 0; fn < 4; fn++) {
                int col = tcol + wc + fn * 16 + li;
#pragma unroll
                for (int j = 0; j < 4; j++) {
                    int a = trow + wr + fm * 16 + g * 4 + j;
                    vT[((size_t)b * 512 + a) * 16384 + col]
                        = f2bf(acc[fm][fn][j] + biasV[a]);
                }
            }
    }
}

// ---------------------------------------------------------------------------
// latT (+ fused dene): latp[ch][bh][d][m] = sum_n vT[d][n]*(P12dec[n][h,m]*DD[n])
// (split-K 32).  Staging values v = P*DD (f32) also accumulated into dacc[8]
// and reduced to denp[(bh*64+m)][ch] at the end.
// ---------------------------------------------------------------------------
__global__ __launch_bounds__(256, 2) void k_latT(const u16* vT, const u16* P12,
                                                 const float* DD, float* latp,
                                                 float* denp)
{
    __shared__ u16 sh2[4096];            // As[2048] | Bs[2048]; reduce as f32[2048]
    u16* As = sh2;
    u16* Bs = sh2 + 2048;
    f32x4 acc[2][2] = {};
    float dacc[8] = {0.f, 0.f, 0.f, 0.f, 0.f, 0.f, 0.f, 0.f};
    int ch = blockIdx.x, bh = blockIdx.z;
    int b = bh >> 3, h = bh & 7;
    int koff = ch * 512;
    int tid = threadIdx.x, wid = tid >> 6, lane = tid & 63;
    int wr = (wid & 1) * 32, wc = (wid >> 1) * 32;
    int lrow = lane & 15, lk = (lane >> 4) * 8;
    const u16* Avt = vT + (size_t)bh * 64 * 16384;
    int nl = tid & 31, m0 = (tid >> 5) * 8;

    for (int kt = 0; kt < 512; kt += 32) {
        __syncthreads();
        {   // stage A: vT rows 64 x 32k
            int row = tid >> 2, kg = tid & 3;
            gload16(Avt + (size_t)row * 16384 + koff + kt + kg * 8, As + (size_t)tid * 8);
        }
        {   // stage B transposed: Bs[m][n], XOR-swizzled; accumulate dene
            int n = koff + kt + nl;
            const u16* src = P12 + ((size_t)b * 16384 + n) * 1024 + h * 64 + m0;
            u16x4 p0 = *(const u16x4*)src;
            u16x4 p1 = *(const u16x4*)(src + 4);
            float ddv = DD[(size_t)bh * 16384 + n];
#pragma unroll
            for (int i = 0; i < 4; i++) {
                int m = m0 + i;
                float v = bf2f(p0[i]) * ddv;
                dacc[i] += v;
                Bs[m * 32 + (nl ^ ((m & 3) << 3))] = f2bf(v);
            }
#pragma unroll
            for (int i = 0; i < 4; i++) {
                int m = m0 + 4 + i;
                float v = bf2f(p1[i]) * ddv;
                dacc[4 + i] += v;
                Bs[m * 32 + (nl ^ ((m & 3) << 3))] = f2bf(v);
            }
        }
        __syncthreads();
        bf16x8 af[2], bfv[2];
#pragma unroll
        for (int fm = 0; fm < 2; fm++)
            af[fm] = *(const bf16x8*)&As[(wr + fm * 16 + lrow) * 32 + lk];
#pragma unroll
        for (int fn = 0; fn < 2; fn++) {
            int m = wc + fn * 16 + lrow;
            bfv[fn] = *(const bf16x8*)&Bs[m * 32 + (lk ^ ((m & 3) << 3))];
        }
#pragma unroll
        for (int fm = 0; fm < 2; fm++)
#pragma unroll
            for (int fn = 0; fn < 2; fn++)
                acc[fm][fn] = __builtin_amdgcn_mfma_f32_16x16x32_bf16(
                    af[fm], bfv[fn], acc[fm][fn], 0, 0, 0);
    }
    float* C = latp + ((size_t)ch * 16 + bh) * 4096;
    int g = lane >> 4, li = lane & 15;
#pragma unroll
    for (int fm = 0; fm < 2; fm++)
#pragma unroll
        for (int fn = 0; fn < 2; fn++)
#pragma unroll
            for (int j = 0; j < 4; j++) {
                int row = wr + fm * 16 + g * 4 + j;   // d
                int col = wc + fn * 16 + li;          // m
                C[row * 64 + col] = acc[fm][fn][j];
            }
    // dene reduce: red[m][nl] = dacc; 64 rows sum 32 partials -> denp.
    __syncthreads();                     // all waves done reading As/Bs
    float* red = (float*)sh2;            // 2048 f32 = 8KB
#pragma unroll
    for (int i = 0; i < 8; i++)
        red[(m0 + i) * 32 + nl] = dacc[i];
    __syncthreads();
    if (tid < 64) {
        float s = 0.f;
        const float* rr = red + tid * 32;
        for (int j = 0; j < 32; j++) s += rr[j];
        denp[(size_t)(bh * 64 + tid) * 32 + ch] = s;
    }
}

// finish latent (+ inline den reduce): latB[bh][m][d] =
//   w * (sum_ch latp[d][m]) / (sum_c denp)    ([pos][d] layout for prep_gd)
__global__ void k_latfin(const float* latp, const float* denp, const float* smix,
                         u16* latB)
{
    int t = blockIdx.x * 256 + threadIdx.x;       // 16*64*64
    int bh = t >> 12, r = t & 4095;
    int d = r >> 6, m = r & 63;
    float w = 1.f / (1.f + __expf(-smix[0]));
    float s = 0.f;
    for (int c = 0; c < 32; c++) s += latp[((size_t)c * 16 + bh) * 4096 + r];
    float dd = 0.f;
    const float* dp = denp + (size_t)(bh * 64 + m) * 32;
    for (int c = 0; c < 32; c++) dd += dp[c];
    latB[(size_t)bh * 4096 + m * 64 + d] = f2bf(w * s / dd);
}

// ---------------------------------------------------------------------------
// prep_gd: G dec half (k<512): G[b][e][k] = sum_d latB[b,h(k)][k&63][d]*Wo[e][..]
// ---------------------------------------------------------------------------
__global__ void prep_gd(const u16* latB, const float* Wo, u16* G)
{
    int idx = blockIdx.x * 256 + threadIdx.x;     // 2*512*512
    int b = idx >> 18;
    int rr = idx & 262143;
    int e = rr >> 9, k = rr & 511;
    int h = k >> 6, dm = k & 63;
    const float* wrow = Wo + (size_t)e * 512 + h * 64;
    const u16* sb = latB + (size_t)(b * 8 + h) * 4096 + dm * 64;
    float s = 0.f;
#pragma unroll
    for (int d0 = 0; d0 < 64; d0 += 4) {
        u16x4 sv = *(const u16x4*)(sb + d0);
        f32x4 wv = *(const f32x4*)(wrow + d0);
        s += bf2f(sv[0]) * wv[0] + bf2f(sv[1]) * wv[1]
           + bf2f(sv[2]) * wv[2] + bf2f(sv[3]) * wv[3];
    }
    G[(size_t)b * 524288 + (size_t)e * 1024 + k] = f2bf(s);
}

// ---------------------------------------------------------------------------
// k_fbig: out(fp32) = P12 @ G[b]^T + bo   (K=1024, BK=64 core)
// ---------------------------------------------------------------------------
__global__ __launch_bounds__(256, 2) void k_fbig(const u16* P12, const u16* G,
                                                 const float* bo, float* out)
{
    __shared__ u16 As[128 * 64], Bs[128 * 64];
    f32x4 acc[4][4] = {};
    int f = blockIdx.y * gridDim.x + blockIdx.x;       // 1024 blocks
    int w = (f & 7) * 128 + (f >> 3);
    int tcol = (w & 3) * 128, trow = (w >> 2) * 128;
    int b = trow >> 14;
    gemm_core64<128, 128, 2, 2>(P12, 1024, G + (size_t)b * 524288, 1024,
                                1024, trow, tcol, As, Bs, acc);
    int tid = threadIdx.x, wid = tid >> 6, lane = tid & 63;
    int wr = (wid & 1) * 64, wc = (wid >> 1) * 64;
    int g = lane >> 4, li = lane & 15;
#pragma unroll
    for (int fm = 0; fm < 4; fm++)
#pragma unroll
        for (int fn = 0; fn < 4; fn++) {
            int col = tcol + wc + fn * 16 + li;
            float bias = bo[col];
#pragma unroll
            for (int j = 0; j < 4; j++) {
                int row = trow + wr + fm * 16 + g * 4 + j;
                out[(size_t)row * 512 + col] = acc[fm][fn][j] + bias;
            }
        }
}

// ---------------------------------------------------------------------------
// Workspace layout (bytes), end ~154 MB (< proven-safe 209.7 MB). No aliases.
// ---------------------------------------------------------------------------
static const size_t XS_OFF   = 0;            // u16 32768x512    (33,554,432)
static const size_t P12_OFF  = 33554432;     // u16 2x16384x1024 (67,108,864)
static const size_t VT_OFF   = 100663296;    // u16 2x512x16384  (33,554,432)
static const size_t CKF_OFF  = 134217728;    // f32 512x512      (1,048,576)
static const size_t CQF_OFF  = 135266304;    // f32 512x512      (1,048,576)
static const size_t WV_OFF   = 136314880;    // u16 512x512      (524,288)
static const size_t BIGB_OFF = 136839168;    // u16 2x1024x1024  (4,194,304)
static const size_t KCF_OFF  = 141033472;    // f32 16x64x64     (262,144)
static const size_t VCT_OFF  = 141295616;    // u16 16x64x64     (131,072)
static const size_t BKQ_OFF  = 141426688;    // f32 1024         (4,096)
static const size_t BV_OFF   = 141430784;    // f32 512          (2,048)
static const size_t CC_OFF   = 141432832;    // f32 2048         (8,192)
static const size_t DENP_OFF = 141441024;    // f32 1024x32      (131,072)
static const size_t DD_OFF   = 141965312;    // f32 16x16384     (1,048,576)
static const size_t LATP_OFF = 143013888;    // f32 32x16x64x64  (8,388,608)
static const size_t LATB_OFF = 151402496;    // u16 16x64x64     (131,072)
static const size_t G_OFF    = 151533568;    // u16 2x512x1024   (2,097,152)
// end: 153,630,720

extern "C" void kernel_launch(void* const* d_in, const int* in_sizes, int n_in,
                              void* d_out, int out_size, void* d_ws, size_t ws_size,
                              hipStream_t stream)
{
    const float* x    = (const float*)d_in[0];
    const float* ctx  = (const float*)d_in[1];
    const float* qg   = (const float*)d_in[2];
    const float* Wx   = (const float*)d_in[3];
    const float* bx   = (const float*)d_in[4];
    const float* Wk   = (const float*)d_in[5];
    const float* bk   = (const float*)d_in[6];
    const float* Wv   = (const float*)d_in[7];
    const float* bv   = (const float*)d_in[8];
    const float* Wcq  = (const float*)d_in[9];
    const float* bcq  = (const float*)d_in[10];
    const float* Wck  = (const float*)d_in[11];
    const float* bck  = (const float*)d_in[12];
    const float* Wcv  = (const float*)d_in[13];
    const float* bcv  = (const float*)d_in[14];
    const float* smix = (const float*)d_in[15];
    const float* Wo   = (const float*)d_in[16];
    const float* bo   = (const float*)d_in[17];

    char* ws = (char*)d_ws;
    u16*   xs    = (u16*)  (ws + XS_OFF);
    u16*   P12   = (u16*)  (ws + P12_OFF);
    u16*   vT    = (u16*)  (ws + VT_OFF);
    float* CKF   = (float*)(ws + CKF_OFF);
    float* CQF   = (float*)(ws + CQF_OFF);
    u16*   wV    = (u16*)  (ws + WV_OFF);
    u16*   BigB  = (u16*)  (ws + BIGB_OFF);
    float* kcf   = (float*)(ws + KCF_OFF);
    u16*   vcT   = (u16*)  (ws + VCT_OFF);
    float* biasKQ= (float*)(ws + BKQ_OFF);
    float* biasV = (float*)(ws + BV_OFF);
    float* CC    = (float*)(ws + CC_OFF);
    float* denp  = (float*)(ws + DENP_OFF);
    float* DD    = (float*)(ws + DD_OFF);
    float* latp  = (float*)(ws + LATP_OFF);
    u16*   latB  = (u16*)  (ws + LATB_OFF);
    u16*   G     = (u16*)  (ws + G_OFF);

    prep_small<<< 3334, 256, 0, stream>>>(Wk, Wcq, Wv, Wx, bk, bcq, bv, bx,
                                          ctx, Wck, bck, Wcv, bcv, smix,
                                          CKF, CQF, wV, biasKQ, biasV, kcf, vcT);
    prep_big  <<<21510, 256, 0, stream>>>(x, CKF, CQF, qg, kcf, biasKQ, vcT, Wo,
                                          xs, BigB, CC, G);

    k_Lvt   <<<3072, 256, 0, stream>>>(xs, BigB, CC, wV, biasV, P12, DD, vT);
    k_latT  <<<dim3( 32,   1, 16), 256, 0, stream>>>(vT, P12, DD, latp, denp);
    k_latfin<<< 256, 256, 0, stream>>>(latp, denp, smix, latB);
    prep_gd <<<2048, 256, 0, stream>>>(latB, Wo, G);
    k_fbig  <<<dim3(  4, 256, 1), 256, 0, stream>>>(P12, G, bo, (float*)d_out);
}